// Round 1
// baseline (1023.064 us; speedup 1.0000x reference)
//
#include <hip/hip_runtime.h>
#include <math.h>

#define NN 50000
#define NE 800000
#define D_IN 64
#define D_HID 256
#define BN_EPS 1e-5f

// ---------------- init: deg=1 (self loop), zero BN accumulators ----------------
__global__ void k_init(float* __restrict__ deg, float* __restrict__ colsum,
                       float* __restrict__ colsumsq, int n) {
    int i = blockIdx.x * blockDim.x + threadIdx.x;
    if (i < n) deg[i] = 1.0f;
    if (i < D_HID) { colsum[i] = 0.f; colsumsq[i] = 0.f; }
}

// ---------------- degree accumulation over edges ----------------
__global__ void k_deg(const int* __restrict__ eidx, float* __restrict__ deg, int E) {
    int e = blockIdx.x * blockDim.x + threadIdx.x;
    if (e < E) atomicAdd(&deg[eidx[E + e]], 1.0f);
}

// ---------------- dinv + self-loop term of aggregation ----------------
__global__ void k_node_init(const float* __restrict__ xs, const float* __restrict__ deg,
                            float* __restrict__ dinv, float* __restrict__ agg, int n) {
    int idx = blockIdx.x * blockDim.x + threadIdx.x;  // over n*64
    if (idx >= n * D_IN) return;
    int i = idx >> 6;
    int k = idx & 63;
    float dv = rsqrtf(deg[i]);      // deg >= 1 always
    agg[idx] = xs[idx] * dv * dv;   // self loop: dinv[i]^2 * xs[i]
    if (k == 0) dinv[i] = dv;
}

// ---------------- edge aggregation in INPUT space (D=64): wave-per-edge ----------------
__global__ void k_edge_agg(const int* __restrict__ eidx, const float* __restrict__ xs,
                           const float* __restrict__ dinv, float* __restrict__ agg, int E) {
    long tid = (long)blockIdx.x * blockDim.x + threadIdx.x;
    int e = (int)(tid >> 6);
    int k = (int)(tid & 63);
    if (e >= E) return;
    int s = eidx[e];
    int d = eidx[E + e];
    float v = xs[s * D_IN + k] * (dinv[s] * dinv[d]);
    atomicAdd(&agg[d * D_IN + k], v);
}

// ---------------- skinny GEMM: [n x 64] @ [64 x 256] + b, optional tanh ----------------
// thread-per-column, W column register-cached, input rows broadcast via LDS
template <int ACT>
__global__ __launch_bounds__(256) void k_gemm64(const float* __restrict__ in,
                                                const float* __restrict__ W,
                                                const float* __restrict__ b,
                                                float* __restrict__ out, int n) {
    int c = threadIdx.x;
    int row0 = blockIdx.x * 64;
    float Wreg[64];
#pragma unroll
    for (int k = 0; k < 64; k++) Wreg[k] = W[k * D_HID + c];
    float bias = b[c];
    __shared__ float rows[4][64];
    for (int rc = 0; rc < 64; rc += 4) {
        int r = rc + (threadIdx.x >> 6);
        int k = threadIdx.x & 63;
        int row = row0 + r;
        rows[threadIdx.x >> 6][k] = (row < n) ? in[row * D_IN + k] : 0.f;
        __syncthreads();
#pragma unroll
        for (int rr = 0; rr < 4; rr++) {
            int orow = row0 + rc + rr;
            if (orow < n) {
                float acc = bias;
#pragma unroll
                for (int kk = 0; kk < 64; kk++) acc += Wreg[kk] * rows[rr][kk];
                if (ACT == 1) acc = tanhf(acc);
                out[orow * D_HID + c] = acc;
            }
        }
        __syncthreads();
    }
}

// ---------------- gate GEMM (256x256) + sigmoid + combine + relu + BN partials ----------------
__global__ __launch_bounds__(256) void k_gate(const float* __restrict__ z,
                                              const float* __restrict__ xl,
                                              const float* __restrict__ Wg,
                                              const float* __restrict__ bg,
                                              float* __restrict__ out,
                                              float* __restrict__ colsum,
                                              float* __restrict__ colsumsq, int n) {
    const int R = 32;
    int c = threadIdx.x;
    int row0 = blockIdx.x * R;
    float bias = bg[c];
    float acc[R];
#pragma unroll
    for (int r = 0; r < R; r++) acc[r] = bias;

    __shared__ float zt[R][64];
    for (int kc = 0; kc < 4; kc++) {
        float Wreg[64];
#pragma unroll
        for (int k = 0; k < 64; k++) Wreg[k] = Wg[(kc * 64 + k) * D_HID + c];
        __syncthreads();  // protect previous tile reads
#pragma unroll
        for (int j = 0; j < 8; j++) {
            int idx = j * 256 + threadIdx.x;  // 0..2047
            int r = idx >> 6;
            int k = idx & 63;
            int row = row0 + r;
            zt[r][k] = (row < n) ? z[row * D_HID + kc * 64 + k] : 0.f;
        }
        __syncthreads();
#pragma unroll
        for (int r = 0; r < R; r++) {
            float a = acc[r];
#pragma unroll
            for (int k = 0; k < 64; k++) a += Wreg[k] * zt[r][k];
            acc[r] = a;
        }
    }

    float ls = 0.f, lsq = 0.f;
#pragma unroll
    for (int r = 0; r < R; r++) {
        int row = row0 + r;
        if (row < n) {
            float g = 1.f / (1.f + expf(-acc[r]));
            float zv = z[row * D_HID + c];
            float xv = xl[row * D_HID + c];
            float o = (1.f - g) * xv + g * zv;
            o = fmaxf(o, 0.f);
            out[row * D_HID + c] = o;
            ls += o;
            lsq += o * o;
        }
    }
    atomicAdd(&colsum[c], ls);
    atomicAdd(&colsumsq[c], lsq);
}

// ---------------- BN finalize: per-column scale/shift ----------------
__global__ void k_bn_final(const float* __restrict__ colsum, const float* __restrict__ colsumsq,
                           const float* __restrict__ gamma, const float* __restrict__ beta,
                           float* __restrict__ scale, float* __restrict__ shift, int n) {
    int c = threadIdx.x;
    float inv_n = 1.0f / (float)n;
    float mu = colsum[c] * inv_n;
    float var = colsumsq[c] * inv_n - mu * mu;
    float sc = gamma[c] * rsqrtf(var + BN_EPS);
    scale[c] = sc;
    shift[c] = beta[c] - mu * sc;
}

// ---------------- BN apply, vectorized ----------------
__global__ void k_bn_apply(float* __restrict__ out, const float* __restrict__ scale,
                           const float* __restrict__ shift, int total4) {
    int i4 = blockIdx.x * blockDim.x + threadIdx.x;
    if (i4 >= total4) return;
    long idx = (long)i4 * 4;
    float4 v = *(float4*)(out + idx);
    int c = (int)(idx & (D_HID - 1));
    v.x = v.x * scale[c + 0] + shift[c + 0];
    v.y = v.y * scale[c + 1] + shift[c + 1];
    v.z = v.z * scale[c + 2] + shift[c + 2];
    v.w = v.w * scale[c + 3] + shift[c + 3];
    *(float4*)(out + idx) = v;
}

extern "C" void kernel_launch(void* const* d_in, const int* in_sizes, int n_in,
                              void* d_out, int out_size, void* d_ws, size_t ws_size,
                              hipStream_t stream) {
    const float* xs     = (const float*)d_in[0];
    const int*   eidx   = (const int*)d_in[1];
    const float* W_gcn  = (const float*)d_in[2];
    const float* b_gcn  = (const float*)d_in[3];
    const float* W_lin  = (const float*)d_in[4];
    const float* b_lin  = (const float*)d_in[5];
    const float* W_gate = (const float*)d_in[6];
    const float* b_gate = (const float*)d_in[7];
    const float* gamma  = (const float*)d_in[8];
    const float* beta   = (const float*)d_in[9];
    float* out = (float*)d_out;

    const int n = in_sizes[0] / D_IN;   // 50000
    const int E = in_sizes[1] / 2;      // 800000

    // workspace layout (256B aligned)
    char* ws = (char*)d_ws;
    size_t off = 0;
    auto alloc = [&](size_t bytes) {
        char* p = ws + off;
        off += (bytes + 255) & ~(size_t)255;
        return p;
    };
    float* deg      = (float*)alloc((size_t)n * 4);
    float* dinv     = (float*)alloc((size_t)n * 4);
    float* agg      = (float*)alloc((size_t)n * D_IN * 4);
    float* z        = (float*)alloc((size_t)n * D_HID * 4);
    float* xl       = (float*)alloc((size_t)n * D_HID * 4);
    float* colsum   = (float*)alloc(D_HID * 4);
    float* colsumsq = (float*)alloc(D_HID * 4);
    float* scale    = (float*)alloc(D_HID * 4);
    float* shift    = (float*)alloc(D_HID * 4);
    (void)ws_size;

    const int B = 256;

    // 1. deg=1, zero BN accumulators
    k_init<<<(n + B - 1) / B, B, 0, stream>>>(deg, colsum, colsumsq, n);
    // 2. degree accumulation
    k_deg<<<(E + B - 1) / B, B, 0, stream>>>(eidx, deg, E);
    // 3. dinv + self-loop init of agg
    k_node_init<<<(n * D_IN + B - 1) / B, B, 0, stream>>>(xs, deg, dinv, agg, n);
    // 4. edge aggregation in input space (wave-per-edge, lane-per-feature)
    {
        long threads = (long)E * 64;
        k_edge_agg<<<(int)((threads + B - 1) / B), B, 0, stream>>>(eidx, xs, dinv, agg, E);
    }
    // 5. z = tanh(agg @ W_gcn + b_gcn)
    k_gemm64<1><<<(n + 63) / 64, B, 0, stream>>>(agg, W_gcn, b_gcn, z, n);
    // 6. xl = xs @ W_lin + b_lin
    k_gemm64<0><<<(n + 63) / 64, B, 0, stream>>>(xs, W_lin, b_lin, xl, n);
    // 7. gate GEMM + sigmoid + combine + relu + BN partial sums
    k_gate<<<(n + 31) / 32, B, 0, stream>>>(z, xl, W_gate, b_gate, out, colsum, colsumsq, n);
    // 8. BN finalize
    k_bn_final<<<1, D_HID, 0, stream>>>(colsum, colsumsq, gamma, beta, scale, shift, n);
    // 9. BN apply
    {
        int total4 = n * D_HID / 4;
        k_bn_apply<<<(total4 + B - 1) / B, B, 0, stream>>>(out, scale, shift, total4);
    }
}

// Round 2
// 465.183 us; speedup vs baseline: 2.1993x; 2.1993x over previous
//
#include <hip/hip_runtime.h>
#include <math.h>

#define NN 50000
#define NE 800000
#define D_IN 64
#define D_HID 256
#define BN_EPS 1e-5f

typedef __attribute__((ext_vector_type(8))) short short8;
typedef __attribute__((ext_vector_type(4))) float f32x4;

static __device__ __forceinline__ unsigned short f2bf(float f) {
    unsigned int u = __builtin_bit_cast(unsigned int, f);
    u += 0x7FFFu + ((u >> 16) & 1u);   // round-to-nearest-even
    return (unsigned short)(u >> 16);
}
static __device__ __forceinline__ float bf2f(unsigned short s) {
    unsigned int u = ((unsigned int)s) << 16;
    return __builtin_bit_cast(float, u);
}

// ---------------- init: deg=1 (self loop), zero BN accumulators ----------------
__global__ void k_init(float* __restrict__ deg, float* __restrict__ colsum,
                       float* __restrict__ colsumsq, int n) {
    int i = blockIdx.x * blockDim.x + threadIdx.x;
    if (i < n) deg[i] = 1.0f;
    if (i < D_HID) { colsum[i] = 0.f; colsumsq[i] = 0.f; }
}

// ---------------- W[K][N] fp32 -> Wt[N][K] bf16 (transposed, frag-contiguous) ----------------
__global__ void k_wconv(const float* __restrict__ W, unsigned short* __restrict__ Wt,
                        int K, int N) {
    int idx = blockIdx.x * blockDim.x + threadIdx.x;
    if (idx >= K * N) return;
    int k = idx / N;
    int nn = idx - k * N;
    Wt[nn * K + k] = f2bf(W[k * N + nn]);
}

// ---------------- degree accumulation over edges ----------------
__global__ void k_deg(const int* __restrict__ eidx, float* __restrict__ deg, int E) {
    int e = blockIdx.x * blockDim.x + threadIdx.x;
    if (e < E) atomicAdd(&deg[eidx[E + e]], 1.0f);
}

// ---------------- dinv + self-loop term of aggregation ----------------
__global__ void k_node_init(const float* __restrict__ xs, const float* __restrict__ deg,
                            float* __restrict__ dinv, float* __restrict__ agg, int n) {
    int idx = blockIdx.x * blockDim.x + threadIdx.x;  // over n*64
    if (idx >= n * D_IN) return;
    int i = idx >> 6;
    int k = idx & 63;
    float dv = rsqrtf(deg[i]);      // deg >= 1 always
    agg[idx] = xs[idx] * dv * dv;   // self loop: dinv[i]^2 * xs[i]
    if (k == 0) dinv[i] = dv;
}

// ---------------- edge aggregation in INPUT space (D=64): wave-per-edge ----------------
__global__ void k_edge_agg(const int* __restrict__ eidx, const float* __restrict__ xs,
                           const float* __restrict__ dinv, float* __restrict__ agg, int E) {
    long tid = (long)blockIdx.x * blockDim.x + threadIdx.x;
    int e = (int)(tid >> 6);
    int k = (int)(tid & 63);
    if (e >= E) return;
    int s = eidx[e];
    int d = eidx[E + e];
    float v = xs[s * D_IN + k] * (dinv[s] * dinv[d]);
    atomicAdd(&agg[d * D_IN + k], v);
}

// ---------------- z_bf = tanh(agg @ W_gcn + b_gcn), MFMA bf16 ----------------
// block: 64 rows x 256 cols; 4 waves, wave wv owns cols [wv*64, wv*64+64)
// A-frag: A[m=lane&15][k=quad*8+j]  (m89-verified layout)
// C/D:    col=lane&15, row=quad*4+reg
__global__ __launch_bounds__(256) void k_zgemm(const float* __restrict__ agg,
                                               const unsigned short* __restrict__ Wt,  // [256][64] bf16
                                               const float* __restrict__ b,
                                               unsigned short* __restrict__ z_bf, int n) {
    int wv = threadIdx.x >> 6;
    int lane = threadIdx.x & 63;
    int l15 = lane & 15;
    int quad = lane >> 4;
    int row0 = blockIdx.x * 64;

    f32x4 acc[4][4];
#pragma unroll
    for (int a = 0; a < 4; a++)
#pragma unroll
        for (int c = 0; c < 4; c++) acc[a][c] = (f32x4){0.f, 0.f, 0.f, 0.f};

#pragma unroll
    for (int kc = 0; kc < 2; kc++) {   // K = 64, 2 steps of 32
        short8 af[4];
#pragma unroll
        for (int tm = 0; tm < 4; tm++) {
            int r = row0 + tm * 16 + l15;
            r = r < n ? r : n - 1;      // clamp: garbage rows predicated in epilogue
            const float* p = agg + (long)r * D_IN + kc * 32 + quad * 8;
            f32x4 f0 = *(const f32x4*)(p);
            f32x4 f1 = *(const f32x4*)(p + 4);
            short8 a;
            a[0] = (short)f2bf(f0.x); a[1] = (short)f2bf(f0.y);
            a[2] = (short)f2bf(f0.z); a[3] = (short)f2bf(f0.w);
            a[4] = (short)f2bf(f1.x); a[5] = (short)f2bf(f1.y);
            a[6] = (short)f2bf(f1.z); a[7] = (short)f2bf(f1.w);
            af[tm] = a;
        }
        short8 bfr[4];
#pragma unroll
        for (int tn = 0; tn < 4; tn++) {
            int c = wv * 64 + tn * 16 + l15;
            bfr[tn] = *(const short8*)(Wt + (long)c * D_IN + kc * 32 + quad * 8);
        }
#pragma unroll
        for (int tm = 0; tm < 4; tm++)
#pragma unroll
            for (int tn = 0; tn < 4; tn++)
                acc[tm][tn] = __builtin_amdgcn_mfma_f32_16x16x32_bf16(af[tm], bfr[tn], acc[tm][tn], 0, 0, 0);
    }

#pragma unroll
    for (int tn = 0; tn < 4; tn++) {
        int col = wv * 64 + tn * 16 + l15;
        float bias = b[col];
#pragma unroll
        for (int tm = 0; tm < 4; tm++) {
#pragma unroll
            for (int r2 = 0; r2 < 4; r2++) {
                int row = row0 + tm * 16 + quad * 4 + r2;
                if (row < n) {
                    float v = tanhf(acc[tm][tn][r2] + bias);
                    z_bf[(long)row * D_HID + col] = f2bf(v);
                }
            }
        }
    }
}

// ---------------- gate GEMM (K=256) + xl GEMM (K=64) + sigmoid/combine/relu + BN partials ----
__global__ __launch_bounds__(256) void k_gate2(const unsigned short* __restrict__ z_bf,
                                               const float* __restrict__ xs,
                                               const unsigned short* __restrict__ Wt_gate, // [256][256] bf16
                                               const unsigned short* __restrict__ Wt_lin,  // [256][64] bf16
                                               const float* __restrict__ bg,
                                               const float* __restrict__ bl,
                                               float* __restrict__ out,
                                               float* __restrict__ colsum,
                                               float* __restrict__ colsumsq, int n) {
    int wv = threadIdx.x >> 6;
    int lane = threadIdx.x & 63;
    int l15 = lane & 15;
    int quad = lane >> 4;
    int row0 = blockIdx.x * 64;

    f32x4 acc1[4][4];  // z @ W_gate
    f32x4 acc2[4][4];  // xs @ W_lin
#pragma unroll
    for (int a = 0; a < 4; a++)
#pragma unroll
        for (int c = 0; c < 4; c++) {
            acc1[a][c] = (f32x4){0.f, 0.f, 0.f, 0.f};
            acc2[a][c] = (f32x4){0.f, 0.f, 0.f, 0.f};
        }

    // ---- xl = xs @ W_lin : K=64, A from fp32 xs with in-flight bf16 convert ----
#pragma unroll
    for (int kc = 0; kc < 2; kc++) {
        short8 af[4];
#pragma unroll
        for (int tm = 0; tm < 4; tm++) {
            int r = row0 + tm * 16 + l15;
            r = r < n ? r : n - 1;
            const float* p = xs + (long)r * D_IN + kc * 32 + quad * 8;
            f32x4 f0 = *(const f32x4*)(p);
            f32x4 f1 = *(const f32x4*)(p + 4);
            short8 a;
            a[0] = (short)f2bf(f0.x); a[1] = (short)f2bf(f0.y);
            a[2] = (short)f2bf(f0.z); a[3] = (short)f2bf(f0.w);
            a[4] = (short)f2bf(f1.x); a[5] = (short)f2bf(f1.y);
            a[6] = (short)f2bf(f1.z); a[7] = (short)f2bf(f1.w);
            af[tm] = a;
        }
        short8 bfr[4];
#pragma unroll
        for (int tn = 0; tn < 4; tn++) {
            int c = wv * 64 + tn * 16 + l15;
            bfr[tn] = *(const short8*)(Wt_lin + (long)c * D_IN + kc * 32 + quad * 8);
        }
#pragma unroll
        for (int tm = 0; tm < 4; tm++)
#pragma unroll
            for (int tn = 0; tn < 4; tn++)
                acc2[tm][tn] = __builtin_amdgcn_mfma_f32_16x16x32_bf16(af[tm], bfr[tn], acc2[tm][tn], 0, 0, 0);
    }

    // ---- logits = z @ W_gate : K=256, A straight from bf16 z_bf ----
#pragma unroll
    for (int kc = 0; kc < 8; kc++) {
        short8 af[4];
#pragma unroll
        for (int tm = 0; tm < 4; tm++) {
            int r = row0 + tm * 16 + l15;
            r = r < n ? r : n - 1;
            af[tm] = *(const short8*)(z_bf + (long)r * D_HID + kc * 32 + quad * 8);
        }
        short8 bfr[4];
#pragma unroll
        for (int tn = 0; tn < 4; tn++) {
            int c = wv * 64 + tn * 16 + l15;
            bfr[tn] = *(const short8*)(Wt_gate + (long)c * D_HID + kc * 32 + quad * 8);
        }
#pragma unroll
        for (int tm = 0; tm < 4; tm++)
#pragma unroll
            for (int tn = 0; tn < 4; tn++)
                acc1[tm][tn] = __builtin_amdgcn_mfma_f32_16x16x32_bf16(af[tm], bfr[tn], acc1[tm][tn], 0, 0, 0);
    }

    // ---- epilogue: sigmoid gate, combine, relu, store, BN partial sums ----
    float ls[4] = {0.f, 0.f, 0.f, 0.f};
    float lsq[4] = {0.f, 0.f, 0.f, 0.f};
#pragma unroll
    for (int tn = 0; tn < 4; tn++) {
        int col = wv * 64 + tn * 16 + l15;
        float bgc = bg[col];
        float blc = bl[col];
#pragma unroll
        for (int tm = 0; tm < 4; tm++) {
#pragma unroll
            for (int r2 = 0; r2 < 4; r2++) {
                int row = row0 + tm * 16 + quad * 4 + r2;
                if (row < n) {
                    float logit = acc1[tm][tn][r2] + bgc;
                    float g = 1.f / (1.f + expf(-logit));
                    float zv = bf2f(z_bf[(long)row * D_HID + col]);
                    float xv = acc2[tm][tn][r2] + blc;
                    float o = (1.f - g) * xv + g * zv;
                    o = fmaxf(o, 0.f);
                    out[(long)row * D_HID + col] = o;
                    ls[tn] += o;
                    lsq[tn] += o * o;
                }
            }
        }
    }
    // reduce across the 4 quads (lanes sharing l15), then 1 atomic per column
#pragma unroll
    for (int tn = 0; tn < 4; tn++) {
        float s = ls[tn];
        float q = lsq[tn];
        s += __shfl_xor(s, 16);
        s += __shfl_xor(s, 32);
        q += __shfl_xor(q, 16);
        q += __shfl_xor(q, 32);
        if (quad == 0) {
            int col = wv * 64 + tn * 16 + l15;
            atomicAdd(&colsum[col], s);
            atomicAdd(&colsumsq[col], q);
        }
    }
}

// ---------------- BN finalize: per-column scale/shift ----------------
__global__ void k_bn_final(const float* __restrict__ colsum, const float* __restrict__ colsumsq,
                           const float* __restrict__ gamma, const float* __restrict__ beta,
                           float* __restrict__ scale, float* __restrict__ shift, int n) {
    int c = threadIdx.x;
    float inv_n = 1.0f / (float)n;
    float mu = colsum[c] * inv_n;
    float var = colsumsq[c] * inv_n - mu * mu;
    float sc = gamma[c] * rsqrtf(var + BN_EPS);
    scale[c] = sc;
    shift[c] = beta[c] - mu * sc;
}

// ---------------- BN apply, vectorized ----------------
__global__ void k_bn_apply(float* __restrict__ out, const float* __restrict__ scale,
                           const float* __restrict__ shift, int total4) {
    int i4 = blockIdx.x * blockDim.x + threadIdx.x;
    if (i4 >= total4) return;
    long idx = (long)i4 * 4;
    float4 v = *(float4*)(out + idx);
    int c = (int)(idx & (D_HID - 1));
    v.x = v.x * scale[c + 0] + shift[c + 0];
    v.y = v.y * scale[c + 1] + shift[c + 1];
    v.z = v.z * scale[c + 2] + shift[c + 2];
    v.w = v.w * scale[c + 3] + shift[c + 3];
    *(float4*)(out + idx) = v;
}

extern "C" void kernel_launch(void* const* d_in, const int* in_sizes, int n_in,
                              void* d_out, int out_size, void* d_ws, size_t ws_size,
                              hipStream_t stream) {
    const float* xs     = (const float*)d_in[0];
    const int*   eidx   = (const int*)d_in[1];
    const float* W_gcn  = (const float*)d_in[2];
    const float* b_gcn  = (const float*)d_in[3];
    const float* W_lin  = (const float*)d_in[4];
    const float* b_lin  = (const float*)d_in[5];
    const float* W_gate = (const float*)d_in[6];
    const float* b_gate = (const float*)d_in[7];
    const float* gamma  = (const float*)d_in[8];
    const float* beta   = (const float*)d_in[9];
    float* out = (float*)d_out;

    const int n = in_sizes[0] / D_IN;   // 50000
    const int E = in_sizes[1] / 2;      // 800000
    const int npad = (n + 63) & ~63;    // padded rows so MFMA tile loads stay in-bounds

    // workspace layout (512B aligned)
    char* ws = (char*)d_ws;
    size_t off = 0;
    auto alloc = [&](size_t bytes) {
        char* p = ws + off;
        off += (bytes + 511) & ~(size_t)511;
        return p;
    };
    float*          deg      = (float*)alloc((size_t)n * 4);
    float*          dinv     = (float*)alloc((size_t)n * 4);
    float*          agg      = (float*)alloc((size_t)npad * D_IN * 4);
    unsigned short* z_bf     = (unsigned short*)alloc((size_t)npad * D_HID * 2);
    unsigned short* Wt_gcn   = (unsigned short*)alloc((size_t)D_IN * D_HID * 2);
    unsigned short* Wt_lin   = (unsigned short*)alloc((size_t)D_IN * D_HID * 2);
    unsigned short* Wt_gate  = (unsigned short*)alloc((size_t)D_HID * D_HID * 2);
    float*          colsum   = (float*)alloc(D_HID * 4);
    float*          colsumsq = (float*)alloc(D_HID * 4);
    float*          scale    = (float*)alloc(D_HID * 4);
    float*          shift    = (float*)alloc(D_HID * 4);
    (void)ws_size;

    const int B = 256;

    // 1. deg=1, zero BN accumulators
    k_init<<<(n + B - 1) / B, B, 0, stream>>>(deg, colsum, colsumsq, n);
    // 1b. transpose+convert weights to bf16 [N][K] layout (frag-contiguous)
    k_wconv<<<(D_IN * D_HID + B - 1) / B, B, 0, stream>>>(W_gcn, Wt_gcn, D_IN, D_HID);
    k_wconv<<<(D_IN * D_HID + B - 1) / B, B, 0, stream>>>(W_lin, Wt_lin, D_IN, D_HID);
    k_wconv<<<(D_HID * D_HID + B - 1) / B, B, 0, stream>>>(W_gate, Wt_gate, D_HID, D_HID);
    // 2. degree accumulation
    k_deg<<<(E + B - 1) / B, B, 0, stream>>>(eidx, deg, E);
    // 3. dinv + self-loop init of agg
    k_node_init<<<(n * D_IN + B - 1) / B, B, 0, stream>>>(xs, deg, dinv, agg, n);
    // 4. edge aggregation in input space (wave-per-edge, lane-per-feature)
    {
        long threads = (long)E * 64;
        k_edge_agg<<<(int)((threads + B - 1) / B), B, 0, stream>>>(eidx, xs, dinv, agg, E);
    }
    // 5. z_bf = tanh(agg @ W_gcn + b_gcn)  [MFMA]
    k_zgemm<<<npad / 64, B, 0, stream>>>(agg, Wt_gcn, b_gcn, z_bf, n);
    // 6+7. gate GEMM + xl GEMM + combine + relu + BN partials  [MFMA]
    k_gate2<<<npad / 64, B, 0, stream>>>(z_bf, xs, Wt_gate, Wt_lin, b_gate, b_lin,
                                         out, colsum, colsumsq, n);
    // 8. BN finalize
    k_bn_final<<<1, D_HID, 0, stream>>>(colsum, colsumsq, gamma, beta, scale, shift, n);
    // 9. BN apply
    {
        int total4 = n * D_HID / 4;
        k_bn_apply<<<(total4 + B - 1) / B, B, 0, stream>>>(out, scale, shift, total4);
    }
}

// Round 3
// 375.312 us; speedup vs baseline: 2.7259x; 1.2395x over previous
//
#include <hip/hip_runtime.h>
#include <math.h>

#define NN 50000
#define NE 800000
#define D_IN 64
#define D_HID 256
#define BN_EPS 1e-5f

typedef __attribute__((ext_vector_type(8))) short short8;
typedef __attribute__((ext_vector_type(4))) float f32x4;

static __device__ __forceinline__ unsigned short f2bf(float f) {
    unsigned int u = __builtin_bit_cast(unsigned int, f);
    u += 0x7FFFu + ((u >> 16) & 1u);   // round-to-nearest-even
    return (unsigned short)(u >> 16);
}
static __device__ __forceinline__ float bf2f(unsigned short s) {
    unsigned int u = ((unsigned int)s) << 16;
    return __builtin_bit_cast(float, u);
}

// ---------------- init: zero edge counters + BN accumulators ----------------
__global__ void k_init(int* __restrict__ cnt, float* __restrict__ colsum,
                       float* __restrict__ colsumsq, int n) {
    int i = blockIdx.x * blockDim.x + threadIdx.x;
    if (i < n) cnt[i] = 0;
    if (i < D_HID) { colsum[i] = 0.f; colsumsq[i] = 0.f; }
}

// ---------------- W[K][N] fp32 -> Wt[N][K] bf16 (transposed, frag-contiguous) ----------------
__global__ void k_wconv(const float* __restrict__ W, unsigned short* __restrict__ Wt,
                        int K, int N) {
    int idx = blockIdx.x * blockDim.x + threadIdx.x;
    if (idx >= K * N) return;
    int k = idx / N;
    int nn = idx - k * N;
    Wt[nn * K + k] = f2bf(W[k * N + nn]);
}

// ---------------- count in-edges per dst ----------------
__global__ void k_count(const int* __restrict__ eidx, int* __restrict__ cnt, int E) {
    int e = blockIdx.x * blockDim.x + threadIdx.x;
    if (e < E) atomicAdd(&cnt[eidx[E + e]], 1);
}

// ---------------- 2-level exclusive scan over cnt[n] ----------------
__global__ void k_scan1(const int* __restrict__ cnt, int* __restrict__ part,
                        int* __restrict__ bsum, int n) {
    __shared__ int s[256];
    int t = threadIdx.x;
    int i = blockIdx.x * 256 + t;
    int v = (i < n) ? cnt[i] : 0;
    s[t] = v;
    __syncthreads();
    for (int d = 1; d < 256; d <<= 1) {
        int t2 = (t >= d) ? s[t - d] : 0;
        __syncthreads();
        s[t] += t2;
        __syncthreads();
    }
    if (i < n) part[i] = s[t] - v;          // exclusive within block
    if (t == 255) bsum[blockIdx.x] = s[255]; // block total
}

__global__ void k_scan2(int* __restrict__ bsum, int nb) {
    __shared__ int s[256];
    int t = threadIdx.x;
    int v = (t < nb) ? bsum[t] : 0;
    s[t] = v;
    __syncthreads();
    for (int d = 1; d < 256; d <<= 1) {
        int t2 = (t >= d) ? s[t - d] : 0;
        __syncthreads();
        s[t] += t2;
        __syncthreads();
    }
    if (t < nb) bsum[t] = s[t] - v;          // exclusive block offsets
}

__global__ void k_scan3(const int* __restrict__ part, const int* __restrict__ bsum,
                        int* __restrict__ offs, int* __restrict__ cursor, int n) {
    int i = blockIdx.x * 256 + threadIdx.x;
    if (i < n) {
        int o = part[i] + bsum[blockIdx.x];
        offs[i] = o;
        cursor[i] = o;
    }
}

// ---------------- scatter edges into CSR-by-dst order ----------------
__global__ void k_scatter(const int* __restrict__ eidx, int* __restrict__ cursor,
                          int* __restrict__ csr_src, int E) {
    int e = blockIdx.x * blockDim.x + threadIdx.x;
    if (e >= E) return;
    int s = eidx[e];
    int d = eidx[E + e];
    int pos = atomicAdd(&cursor[d], 1);
    csr_src[pos] = s;
}

// ---------------- dinv + pre-scaled features: xscaled[i] = xs[i]*dinv[i] ----------------
__global__ void k_prep(const float* __restrict__ xs, const int* __restrict__ cnt,
                       float* __restrict__ dinv, float* __restrict__ xscaled, int n) {
    int idx = blockIdx.x * blockDim.x + threadIdx.x;  // over n*64
    if (idx >= n * D_IN) return;
    int i = idx >> 6;
    int k = idx & 63;
    float dv = rsqrtf(1.0f + (float)cnt[i]);   // deg = in-count + self loop
    xscaled[idx] = xs[idx] * dv;
    if (k == 0) dinv[i] = dv;
}

// ---------------- gather aggregation: wave per node, lane per feature ----------------
// agg[d] = dinv[d] * ( xscaled[d] + sum_{src in N(d)} xscaled[src] )
__global__ __launch_bounds__(256) void k_gather(const int* __restrict__ csr_src,
                                                const int* __restrict__ offs,
                                                const int* __restrict__ cnt,
                                                const float* __restrict__ xscaled,
                                                const float* __restrict__ dinv,
                                                float* __restrict__ agg, int n) {
    int wv = threadIdx.x >> 6;
    int lane = threadIdx.x & 63;
    int i = blockIdx.x * 4 + wv;
    if (i >= n) return;
    int start = offs[i];
    int c = cnt[i];
    float acc = xscaled[(long)i * D_IN + lane];  // self loop (pre-scaled)
    for (int base = 0; base < c; base += 64) {
        int m = c - base;
        m = m < 64 ? m : 64;
        int idx = (lane < m) ? csr_src[start + base + lane] : 0;
        int j = 0;
        // 4-way unrolled broadcast+gather to keep loads in flight
        for (; j + 4 <= m; j += 4) {
            int s0 = __shfl(idx, j + 0);
            int s1 = __shfl(idx, j + 1);
            int s2 = __shfl(idx, j + 2);
            int s3 = __shfl(idx, j + 3);
            float v0 = xscaled[(long)s0 * D_IN + lane];
            float v1 = xscaled[(long)s1 * D_IN + lane];
            float v2 = xscaled[(long)s2 * D_IN + lane];
            float v3 = xscaled[(long)s3 * D_IN + lane];
            acc += v0 + v1 + v2 + v3;
        }
        for (; j < m; j++) {
            int s0 = __shfl(idx, j);
            acc += xscaled[(long)s0 * D_IN + lane];
        }
    }
    agg[(long)i * D_IN + lane] = acc * dinv[i];
}

// ---------------- z_bf = tanh(agg @ W_gcn + b_gcn), MFMA bf16 ----------------
__global__ __launch_bounds__(256) void k_zgemm(const float* __restrict__ agg,
                                               const unsigned short* __restrict__ Wt,  // [256][64] bf16
                                               const float* __restrict__ b,
                                               unsigned short* __restrict__ z_bf, int n) {
    int wv = threadIdx.x >> 6;
    int lane = threadIdx.x & 63;
    int l15 = lane & 15;
    int quad = lane >> 4;
    int row0 = blockIdx.x * 64;

    f32x4 acc[4][4];
#pragma unroll
    for (int a = 0; a < 4; a++)
#pragma unroll
        for (int c = 0; c < 4; c++) acc[a][c] = (f32x4){0.f, 0.f, 0.f, 0.f};

#pragma unroll
    for (int kc = 0; kc < 2; kc++) {   // K = 64, 2 steps of 32
        short8 af[4];
#pragma unroll
        for (int tm = 0; tm < 4; tm++) {
            int r = row0 + tm * 16 + l15;
            r = r < n ? r : n - 1;      // clamp: garbage rows predicated in epilogue
            const float* p = agg + (long)r * D_IN + kc * 32 + quad * 8;
            f32x4 f0 = *(const f32x4*)(p);
            f32x4 f1 = *(const f32x4*)(p + 4);
            short8 a;
            a[0] = (short)f2bf(f0.x); a[1] = (short)f2bf(f0.y);
            a[2] = (short)f2bf(f0.z); a[3] = (short)f2bf(f0.w);
            a[4] = (short)f2bf(f1.x); a[5] = (short)f2bf(f1.y);
            a[6] = (short)f2bf(f1.z); a[7] = (short)f2bf(f1.w);
            af[tm] = a;
        }
        short8 bfr[4];
#pragma unroll
        for (int tn = 0; tn < 4; tn++) {
            int c = wv * 64 + tn * 16 + l15;
            bfr[tn] = *(const short8*)(Wt + (long)c * D_IN + kc * 32 + quad * 8);
        }
#pragma unroll
        for (int tm = 0; tm < 4; tm++)
#pragma unroll
            for (int tn = 0; tn < 4; tn++)
                acc[tm][tn] = __builtin_amdgcn_mfma_f32_16x16x32_bf16(af[tm], bfr[tn], acc[tm][tn], 0, 0, 0);
    }

#pragma unroll
    for (int tn = 0; tn < 4; tn++) {
        int col = wv * 64 + tn * 16 + l15;
        float bias = b[col];
#pragma unroll
        for (int tm = 0; tm < 4; tm++) {
#pragma unroll
            for (int r2 = 0; r2 < 4; r2++) {
                int row = row0 + tm * 16 + quad * 4 + r2;
                if (row < n) {
                    float v = tanhf(acc[tm][tn][r2] + bias);
                    z_bf[(long)row * D_HID + col] = f2bf(v);
                }
            }
        }
    }
}

// ---------------- gate GEMM (K=256) + xl GEMM (K=64) + sigmoid/combine/relu + BN partials ----
__global__ __launch_bounds__(256) void k_gate2(const unsigned short* __restrict__ z_bf,
                                               const float* __restrict__ xs,
                                               const unsigned short* __restrict__ Wt_gate, // [256][256] bf16
                                               const unsigned short* __restrict__ Wt_lin,  // [256][64] bf16
                                               const float* __restrict__ bg,
                                               const float* __restrict__ bl,
                                               float* __restrict__ out,
                                               float* __restrict__ colsum,
                                               float* __restrict__ colsumsq, int n) {
    int wv = threadIdx.x >> 6;
    int lane = threadIdx.x & 63;
    int l15 = lane & 15;
    int quad = lane >> 4;
    int row0 = blockIdx.x * 64;

    f32x4 acc1[4][4];  // z @ W_gate
    f32x4 acc2[4][4];  // xs @ W_lin
#pragma unroll
    for (int a = 0; a < 4; a++)
#pragma unroll
        for (int c = 0; c < 4; c++) {
            acc1[a][c] = (f32x4){0.f, 0.f, 0.f, 0.f};
            acc2[a][c] = (f32x4){0.f, 0.f, 0.f, 0.f};
        }

    // ---- xl = xs @ W_lin : K=64, A from fp32 xs with in-flight bf16 convert ----
#pragma unroll
    for (int kc = 0; kc < 2; kc++) {
        short8 af[4];
#pragma unroll
        for (int tm = 0; tm < 4; tm++) {
            int r = row0 + tm * 16 + l15;
            r = r < n ? r : n - 1;
            const float* p = xs + (long)r * D_IN + kc * 32 + quad * 8;
            f32x4 f0 = *(const f32x4*)(p);
            f32x4 f1 = *(const f32x4*)(p + 4);
            short8 a;
            a[0] = (short)f2bf(f0.x); a[1] = (short)f2bf(f0.y);
            a[2] = (short)f2bf(f0.z); a[3] = (short)f2bf(f0.w);
            a[4] = (short)f2bf(f1.x); a[5] = (short)f2bf(f1.y);
            a[6] = (short)f2bf(f1.z); a[7] = (short)f2bf(f1.w);
            af[tm] = a;
        }
        short8 bfr[4];
#pragma unroll
        for (int tn = 0; tn < 4; tn++) {
            int c = wv * 64 + tn * 16 + l15;
            bfr[tn] = *(const short8*)(Wt_lin + (long)c * D_IN + kc * 32 + quad * 8);
        }
#pragma unroll
        for (int tm = 0; tm < 4; tm++)
#pragma unroll
            for (int tn = 0; tn < 4; tn++)
                acc2[tm][tn] = __builtin_amdgcn_mfma_f32_16x16x32_bf16(af[tm], bfr[tn], acc2[tm][tn], 0, 0, 0);
    }

    // ---- logits = z @ W_gate : K=256, A straight from bf16 z_bf ----
#pragma unroll
    for (int kc = 0; kc < 8; kc++) {
        short8 af[4];
#pragma unroll
        for (int tm = 0; tm < 4; tm++) {
            int r = row0 + tm * 16 + l15;
            r = r < n ? r : n - 1;
            af[tm] = *(const short8*)(z_bf + (long)r * D_HID + kc * 32 + quad * 8);
        }
        short8 bfr[4];
#pragma unroll
        for (int tn = 0; tn < 4; tn++) {
            int c = wv * 64 + tn * 16 + l15;
            bfr[tn] = *(const short8*)(Wt_gate + (long)c * D_HID + kc * 32 + quad * 8);
        }
#pragma unroll
        for (int tm = 0; tm < 4; tm++)
#pragma unroll
            for (int tn = 0; tn < 4; tn++)
                acc1[tm][tn] = __builtin_amdgcn_mfma_f32_16x16x32_bf16(af[tm], bfr[tn], acc1[tm][tn], 0, 0, 0);
    }

    // ---- epilogue: sigmoid gate, combine, relu, store, BN partial sums ----
    float ls[4] = {0.f, 0.f, 0.f, 0.f};
    float lsq[4] = {0.f, 0.f, 0.f, 0.f};
#pragma unroll
    for (int tn = 0; tn < 4; tn++) {
        int col = wv * 64 + tn * 16 + l15;
        float bgc = bg[col];
        float blc = bl[col];
#pragma unroll
        for (int tm = 0; tm < 4; tm++) {
#pragma unroll
            for (int r2 = 0; r2 < 4; r2++) {
                int row = row0 + tm * 16 + quad * 4 + r2;
                if (row < n) {
                    float logit = acc1[tm][tn][r2] + bgc;
                    float g = 1.f / (1.f + expf(-logit));
                    float zv = bf2f(z_bf[(long)row * D_HID + col]);
                    float xv = acc2[tm][tn][r2] + blc;
                    float o = (1.f - g) * xv + g * zv;
                    o = fmaxf(o, 0.f);
                    out[(long)row * D_HID + col] = o;
                    ls[tn] += o;
                    lsq[tn] += o * o;
                }
            }
        }
    }
    // reduce across the 4 quads (lanes sharing l15), then 1 atomic per column
#pragma unroll
    for (int tn = 0; tn < 4; tn++) {
        float s = ls[tn];
        float q = lsq[tn];
        s += __shfl_xor(s, 16);
        s += __shfl_xor(s, 32);
        q += __shfl_xor(q, 16);
        q += __shfl_xor(q, 32);
        if (quad == 0) {
            int col = wv * 64 + tn * 16 + l15;
            atomicAdd(&colsum[col], s);
            atomicAdd(&colsumsq[col], q);
        }
    }
}

// ---------------- BN finalize: per-column scale/shift ----------------
__global__ void k_bn_final(const float* __restrict__ colsum, const float* __restrict__ colsumsq,
                           const float* __restrict__ gamma, const float* __restrict__ beta,
                           float* __restrict__ scale, float* __restrict__ shift, int n) {
    int c = threadIdx.x;
    float inv_n = 1.0f / (float)n;
    float mu = colsum[c] * inv_n;
    float var = colsumsq[c] * inv_n - mu * mu;
    float sc = gamma[c] * rsqrtf(var + BN_EPS);
    scale[c] = sc;
    shift[c] = beta[c] - mu * sc;
}

// ---------------- BN apply, vectorized ----------------
__global__ void k_bn_apply(float* __restrict__ out, const float* __restrict__ scale,
                           const float* __restrict__ shift, int total4) {
    int i4 = blockIdx.x * blockDim.x + threadIdx.x;
    if (i4 >= total4) return;
    long idx = (long)i4 * 4;
    float4 v = *(float4*)(out + idx);
    int c = (int)(idx & (D_HID - 1));
    v.x = v.x * scale[c + 0] + shift[c + 0];
    v.y = v.y * scale[c + 1] + shift[c + 1];
    v.z = v.z * scale[c + 2] + shift[c + 2];
    v.w = v.w * scale[c + 3] + shift[c + 3];
    *(float4*)(out + idx) = v;
}

extern "C" void kernel_launch(void* const* d_in, const int* in_sizes, int n_in,
                              void* d_out, int out_size, void* d_ws, size_t ws_size,
                              hipStream_t stream) {
    const float* xs     = (const float*)d_in[0];
    const int*   eidx   = (const int*)d_in[1];
    const float* W_gcn  = (const float*)d_in[2];
    const float* b_gcn  = (const float*)d_in[3];
    const float* W_lin  = (const float*)d_in[4];
    const float* b_lin  = (const float*)d_in[5];
    const float* W_gate = (const float*)d_in[6];
    const float* b_gate = (const float*)d_in[7];
    const float* gamma  = (const float*)d_in[8];
    const float* beta   = (const float*)d_in[9];
    float* out = (float*)d_out;

    const int n = in_sizes[0] / D_IN;   // 50000
    const int E = in_sizes[1] / 2;      // 800000
    const int npad = (n + 63) & ~63;

    // workspace layout (512B aligned)
    char* ws = (char*)d_ws;
    size_t off = 0;
    auto alloc = [&](size_t bytes) {
        char* p = ws + off;
        off += (bytes + 511) & ~(size_t)511;
        return p;
    };
    int*            cnt      = (int*)alloc((size_t)n * 4);
    int*            part     = (int*)alloc((size_t)n * 4);
    int*            bsum     = (int*)alloc(1024);
    int*            offs     = (int*)alloc((size_t)n * 4);
    int*            cursor   = (int*)alloc((size_t)n * 4);
    int*            csr_src  = (int*)alloc((size_t)E * 4);
    float*          dinv     = (float*)alloc((size_t)n * 4);
    float*          xscaled  = (float*)alloc((size_t)n * D_IN * 4);
    float*          agg      = (float*)alloc((size_t)npad * D_IN * 4);
    unsigned short* z_bf     = (unsigned short*)alloc((size_t)npad * D_HID * 2);
    unsigned short* Wt_gcn   = (unsigned short*)alloc((size_t)D_IN * D_HID * 2);
    unsigned short* Wt_lin   = (unsigned short*)alloc((size_t)D_IN * D_HID * 2);
    unsigned short* Wt_gate  = (unsigned short*)alloc((size_t)D_HID * D_HID * 2);
    float*          colsum   = (float*)alloc(D_HID * 4);
    float*          colsumsq = (float*)alloc(D_HID * 4);
    float*          scale    = (float*)alloc(D_HID * 4);
    float*          shift    = (float*)alloc(D_HID * 4);
    (void)ws_size;

    const int B = 256;
    const int nb = (n + 255) / 256;   // scan blocks (196 <= 256)

    // 1. zero counters + BN accumulators
    k_init<<<(n + B - 1) / B, B, 0, stream>>>(cnt, colsum, colsumsq, n);
    // 1b. weights -> bf16 transposed
    k_wconv<<<(D_IN * D_HID + B - 1) / B, B, 0, stream>>>(W_gcn, Wt_gcn, D_IN, D_HID);
    k_wconv<<<(D_IN * D_HID + B - 1) / B, B, 0, stream>>>(W_lin, Wt_lin, D_IN, D_HID);
    k_wconv<<<(D_HID * D_HID + B - 1) / B, B, 0, stream>>>(W_gate, Wt_gate, D_HID, D_HID);
    // 2. count in-edges per node
    k_count<<<(E + B - 1) / B, B, 0, stream>>>(eidx, cnt, E);
    // 3. exclusive scan -> offsets, init cursors
    k_scan1<<<nb, 256, 0, stream>>>(cnt, part, bsum, n);
    k_scan2<<<1, 256, 0, stream>>>(bsum, nb);
    k_scan3<<<nb, 256, 0, stream>>>(part, bsum, offs, cursor, n);
    // 4. scatter edges to CSR-by-dst
    k_scatter<<<(E + B - 1) / B, B, 0, stream>>>(eidx, cursor, csr_src, E);
    // 5. dinv + pre-scaled features
    k_prep<<<(n * D_IN + B - 1) / B, B, 0, stream>>>(xs, cnt, dinv, xscaled, n);
    // 6. gather aggregation (wave per node)
    k_gather<<<(n + 3) / 4, B, 0, stream>>>(csr_src, offs, cnt, xscaled, dinv, agg, n);
    // 7. z_bf = tanh(agg @ W_gcn + b_gcn)  [MFMA]
    k_zgemm<<<npad / 64, B, 0, stream>>>(agg, Wt_gcn, b_gcn, z_bf, n);
    // 8. gate GEMM + xl GEMM + combine + relu + BN partials  [MFMA]
    k_gate2<<<npad / 64, B, 0, stream>>>(z_bf, xs, Wt_gate, Wt_lin, b_gate, b_lin,
                                         out, colsum, colsumsq, n);
    // 9. BN finalize
    k_bn_final<<<1, D_HID, 0, stream>>>(colsum, colsumsq, gamma, beta, scale, shift, n);
    // 10. BN apply
    {
        int total4 = n * D_HID / 4;
        k_bn_apply<<<(total4 + B - 1) / B, B, 0, stream>>>(out, scale, shift, total4);
    }
}

// Round 4
// 314.847 us; speedup vs baseline: 3.2494x; 1.1920x over previous
//
#include <hip/hip_runtime.h>
#include <math.h>

#define NN 50000
#define NE 800000
#define D_IN 64
#define D_HID 256
#define BN_EPS 1e-5f
#define ZSTR 264   // z-tile LDS row stride in shorts (+8 pad: 16B-aligned rows, even bank load)

typedef __attribute__((ext_vector_type(8))) short short8;
typedef __attribute__((ext_vector_type(4))) float f32x4;

static __device__ __forceinline__ unsigned short f2bf(float f) {
    unsigned int u = __builtin_bit_cast(unsigned int, f);
    u += 0x7FFFu + ((u >> 16) & 1u);   // round-to-nearest-even
    return (unsigned short)(u >> 16);
}
static __device__ __forceinline__ float bf2f(unsigned short s) {
    unsigned int u = ((unsigned int)s) << 16;
    return __builtin_bit_cast(float, u);
}

// ---------------- init: zero edge counters + BN accumulators ----------------
__global__ void k_init(int* __restrict__ cnt, float* __restrict__ colsum,
                       float* __restrict__ colsumsq, int n) {
    int i = blockIdx.x * blockDim.x + threadIdx.x;
    if (i < n) cnt[i] = 0;
    if (i < D_HID) { colsum[i] = 0.f; colsumsq[i] = 0.f; }
}

// ---------------- W[K][N] fp32 -> Wt[N][K] bf16 (transposed, frag-contiguous) ----------------
__global__ void k_wconv(const float* __restrict__ W, unsigned short* __restrict__ Wt,
                        int K, int N) {
    int idx = blockIdx.x * blockDim.x + threadIdx.x;
    if (idx >= K * N) return;
    int k = idx / N;
    int nn = idx - k * N;
    Wt[nn * K + k] = f2bf(W[k * N + nn]);
}

// ---------------- count in-edges per dst ----------------
__global__ void k_count(const int* __restrict__ eidx, int* __restrict__ cnt, int E) {
    int e = blockIdx.x * blockDim.x + threadIdx.x;
    if (e < E) atomicAdd(&cnt[eidx[E + e]], 1);
}

// ---------------- 2-level exclusive scan over cnt[n] ----------------
__global__ void k_scan1(const int* __restrict__ cnt, int* __restrict__ part,
                        int* __restrict__ bsum, int n) {
    __shared__ int s[256];
    int t = threadIdx.x;
    int i = blockIdx.x * 256 + t;
    int v = (i < n) ? cnt[i] : 0;
    s[t] = v;
    __syncthreads();
    for (int d = 1; d < 256; d <<= 1) {
        int t2 = (t >= d) ? s[t - d] : 0;
        __syncthreads();
        s[t] += t2;
        __syncthreads();
    }
    if (i < n) part[i] = s[t] - v;
    if (t == 255) bsum[blockIdx.x] = s[255];
}

__global__ void k_scan2(int* __restrict__ bsum, int nb) {
    __shared__ int s[256];
    int t = threadIdx.x;
    int v = (t < nb) ? bsum[t] : 0;
    s[t] = v;
    __syncthreads();
    for (int d = 1; d < 256; d <<= 1) {
        int t2 = (t >= d) ? s[t - d] : 0;
        __syncthreads();
        s[t] += t2;
        __syncthreads();
    }
    if (t < nb) bsum[t] = s[t] - v;
}

__global__ void k_scan3(const int* __restrict__ part, const int* __restrict__ bsum,
                        int* __restrict__ offs, int* __restrict__ cursor, int n) {
    int i = blockIdx.x * 256 + threadIdx.x;
    if (i < n) {
        int o = part[i] + bsum[blockIdx.x];
        offs[i] = o;
        cursor[i] = o;
    }
}

// ---------------- scatter edges into CSR-by-dst order ----------------
__global__ void k_scatter(const int* __restrict__ eidx, int* __restrict__ cursor,
                          int* __restrict__ csr_src, int E) {
    int e = blockIdx.x * blockDim.x + threadIdx.x;
    if (e >= E) return;
    int s = eidx[e];
    int d = eidx[E + e];
    int pos = atomicAdd(&cursor[d], 1);
    csr_src[pos] = s;
}

// ---------------- dinv + bf16 feature arrays: xscaled = xs*dinv, xs_bf = xs ----------------
__global__ void k_prep(const float* __restrict__ xs, const int* __restrict__ cnt,
                       float* __restrict__ dinv, unsigned short* __restrict__ xscaled,
                       unsigned short* __restrict__ xs_bf, int n) {
    int idx = blockIdx.x * blockDim.x + threadIdx.x;  // over n*64
    if (idx >= n * D_IN) return;
    int i = idx >> 6;
    int k = idx & 63;
    float dv = rsqrtf(1.0f + (float)cnt[i]);
    float x = xs[idx];
    xscaled[idx] = f2bf(x * dv);
    xs_bf[idx] = f2bf(x);
    if (k == 0) dinv[i] = dv;
}

// ---------------- gather aggregation: wave per node, lane per feature (bf16) ----------------
// agg_bf[d] = bf16( dinv[d] * ( xscaled[d] + sum_{src in N(d)} xscaled[src] ) )
__global__ __launch_bounds__(256) void k_gather(const int* __restrict__ csr_src,
                                                const int* __restrict__ offs,
                                                const int* __restrict__ cnt,
                                                const unsigned short* __restrict__ xscaled,
                                                const float* __restrict__ dinv,
                                                unsigned short* __restrict__ agg_bf, int n) {
    int wv = threadIdx.x >> 6;
    int lane = threadIdx.x & 63;
    int i = blockIdx.x * 4 + wv;
    if (i >= n) return;
    int start = offs[i];
    int c = cnt[i];
    float acc = bf2f(xscaled[(long)i * D_IN + lane]);  // self loop (pre-scaled)
    for (int base = 0; base < c; base += 64) {
        int m = c - base;
        m = m < 64 ? m : 64;
        int idx = (lane < m) ? csr_src[start + base + lane] : 0;
        int j = 0;
        for (; j + 4 <= m; j += 4) {
            int s0 = __shfl(idx, j + 0);
            int s1 = __shfl(idx, j + 1);
            int s2 = __shfl(idx, j + 2);
            int s3 = __shfl(idx, j + 3);
            float v0 = bf2f(xscaled[(long)s0 * D_IN + lane]);
            float v1 = bf2f(xscaled[(long)s1 * D_IN + lane]);
            float v2 = bf2f(xscaled[(long)s2 * D_IN + lane]);
            float v3 = bf2f(xscaled[(long)s3 * D_IN + lane]);
            acc += v0 + v1 + v2 + v3;
        }
        for (; j < m; j++) {
            int s0 = __shfl(idx, j);
            acc += bf2f(xscaled[(long)s0 * D_IN + lane]);
        }
    }
    agg_bf[(long)i * D_IN + lane] = f2bf(acc * dinv[i]);
}

// ---------------- fused: z GEMM -> LDS -> gate GEMM + lin GEMM + epilogue + BN partials ----
// block = 64 rows x 256 cols, 4 waves; wave wv owns cols [wv*64, wv*64+64)
// A-frag layout: A[m=lane&15][k=quad*8+j]; C/D: col=lane&15, row=quad*4+reg
__global__ __launch_bounds__(256) void k_fused(const unsigned short* __restrict__ agg_bf,  // [npad][64]
                                               const unsigned short* __restrict__ xs_bf,   // [npad][64]
                                               const unsigned short* __restrict__ Wt_gcn,  // [256][64]
                                               const unsigned short* __restrict__ Wt_lin,  // [256][64]
                                               const unsigned short* __restrict__ Wt_gate, // [256][256]
                                               const float* __restrict__ b_gcn,
                                               const float* __restrict__ bg,
                                               const float* __restrict__ bl,
                                               unsigned short* __restrict__ out_pre,       // [npad][256] bf16
                                               float* __restrict__ colsum,
                                               float* __restrict__ colsumsq, int n) {
    __shared__ unsigned short z_lds[64 * ZSTR];   // 33 KB

    int wv = threadIdx.x >> 6;
    int lane = threadIdx.x & 63;
    int l15 = lane & 15;
    int quad = lane >> 4;
    int row0 = blockIdx.x * 64;

    // ---- phase A: z = tanh(agg @ W_gcn + b_gcn), K=64 ----
    {
        f32x4 accz[4][4];
#pragma unroll
        for (int a = 0; a < 4; a++)
#pragma unroll
            for (int c = 0; c < 4; c++) accz[a][c] = (f32x4){0.f, 0.f, 0.f, 0.f};
#pragma unroll
        for (int kc = 0; kc < 2; kc++) {
            short8 af[4];
#pragma unroll
            for (int tm = 0; tm < 4; tm++)
                af[tm] = *(const short8*)(agg_bf + (long)(row0 + tm * 16 + l15) * D_IN + kc * 32 + quad * 8);
            short8 bfr[4];
#pragma unroll
            for (int tn = 0; tn < 4; tn++)
                bfr[tn] = *(const short8*)(Wt_gcn + (long)(wv * 64 + tn * 16 + l15) * D_IN + kc * 32 + quad * 8);
#pragma unroll
            for (int tm = 0; tm < 4; tm++)
#pragma unroll
                for (int tn = 0; tn < 4; tn++)
                    accz[tm][tn] = __builtin_amdgcn_mfma_f32_16x16x32_bf16(af[tm], bfr[tn], accz[tm][tn], 0, 0, 0);
        }
        // tanh + write z tile to LDS (bf16)
#pragma unroll
        for (int tn = 0; tn < 4; tn++) {
            int col = wv * 64 + tn * 16 + l15;
            float bias = b_gcn[col];
#pragma unroll
            for (int tm = 0; tm < 4; tm++)
#pragma unroll
                for (int r2 = 0; r2 < 4; r2++) {
                    int rl = tm * 16 + quad * 4 + r2;
                    float v = tanhf(accz[tm][tn][r2] + bias);
                    z_lds[rl * ZSTR + col] = f2bf(v);
                }
        }
    }
    __syncthreads();

    // ---- phase B1: xl = xs @ W_lin, K=64 ----
    f32x4 acc2[4][4];
#pragma unroll
    for (int a = 0; a < 4; a++)
#pragma unroll
        for (int c = 0; c < 4; c++) acc2[a][c] = (f32x4){0.f, 0.f, 0.f, 0.f};
#pragma unroll
    for (int kc = 0; kc < 2; kc++) {
        short8 af[4];
#pragma unroll
        for (int tm = 0; tm < 4; tm++)
            af[tm] = *(const short8*)(xs_bf + (long)(row0 + tm * 16 + l15) * D_IN + kc * 32 + quad * 8);
        short8 bfr[4];
#pragma unroll
        for (int tn = 0; tn < 4; tn++)
            bfr[tn] = *(const short8*)(Wt_lin + (long)(wv * 64 + tn * 16 + l15) * D_IN + kc * 32 + quad * 8);
#pragma unroll
        for (int tm = 0; tm < 4; tm++)
#pragma unroll
            for (int tn = 0; tn < 4; tn++)
                acc2[tm][tn] = __builtin_amdgcn_mfma_f32_16x16x32_bf16(af[tm], bfr[tn], acc2[tm][tn], 0, 0, 0);
    }

    // ---- phase B2: logits = z @ W_gate, K=256, A-frags from LDS ----
    f32x4 acc1[4][4];
#pragma unroll
    for (int a = 0; a < 4; a++)
#pragma unroll
        for (int c = 0; c < 4; c++) acc1[a][c] = (f32x4){0.f, 0.f, 0.f, 0.f};
#pragma unroll
    for (int kc = 0; kc < 8; kc++) {
        short8 af[4];
#pragma unroll
        for (int tm = 0; tm < 4; tm++)
            af[tm] = *(const short8*)(&z_lds[(tm * 16 + l15) * ZSTR + kc * 32 + quad * 8]);
        short8 bfr[4];
#pragma unroll
        for (int tn = 0; tn < 4; tn++)
            bfr[tn] = *(const short8*)(Wt_gate + (long)(wv * 64 + tn * 16 + l15) * D_HID + kc * 32 + quad * 8);
#pragma unroll
        for (int tm = 0; tm < 4; tm++)
#pragma unroll
            for (int tn = 0; tn < 4; tn++)
                acc1[tm][tn] = __builtin_amdgcn_mfma_f32_16x16x32_bf16(af[tm], bfr[tn], acc1[tm][tn], 0, 0, 0);
    }

    // ---- epilogue: sigmoid gate, combine, relu, store bf16, BN partials ----
    float ls[4] = {0.f, 0.f, 0.f, 0.f};
    float lsq[4] = {0.f, 0.f, 0.f, 0.f};
#pragma unroll
    for (int tn = 0; tn < 4; tn++) {
        int col = wv * 64 + tn * 16 + l15;
        float bgc = bg[col];
        float blc = bl[col];
#pragma unroll
        for (int tm = 0; tm < 4; tm++)
#pragma unroll
            for (int r2 = 0; r2 < 4; r2++) {
                int rl = tm * 16 + quad * 4 + r2;
                int row = row0 + rl;
                if (row < n) {
                    float logit = acc1[tm][tn][r2] + bgc;
                    float g = 1.f / (1.f + expf(-logit));
                    float zv = bf2f(z_lds[rl * ZSTR + col]);
                    float xv = acc2[tm][tn][r2] + blc;
                    float o = (1.f - g) * xv + g * zv;
                    o = fmaxf(o, 0.f);
                    out_pre[(long)row * D_HID + col] = f2bf(o);
                    ls[tn] += o;
                    lsq[tn] += o * o;
                }
            }
    }
#pragma unroll
    for (int tn = 0; tn < 4; tn++) {
        float s = ls[tn];
        float q = lsq[tn];
        s += __shfl_xor(s, 16);
        s += __shfl_xor(s, 32);
        q += __shfl_xor(q, 16);
        q += __shfl_xor(q, 32);
        if (quad == 0) {
            int col = wv * 64 + tn * 16 + l15;
            atomicAdd(&colsum[col], s);
            atomicAdd(&colsumsq[col], q);
        }
    }
}

// ---------------- BN finalize: per-column scale/shift ----------------
__global__ void k_bn_final(const float* __restrict__ colsum, const float* __restrict__ colsumsq,
                           const float* __restrict__ gamma, const float* __restrict__ beta,
                           float* __restrict__ scale, float* __restrict__ shift, int n) {
    int c = threadIdx.x;
    float inv_n = 1.0f / (float)n;
    float mu = colsum[c] * inv_n;
    float var = colsumsq[c] * inv_n - mu * mu;
    float sc = gamma[c] * rsqrtf(var + BN_EPS);
    scale[c] = sc;
    shift[c] = beta[c] - mu * sc;
}

// ---------------- BN apply: bf16 in -> fp32 out ----------------
__global__ void k_bn_apply(const unsigned short* __restrict__ op, float* __restrict__ out,
                           const float* __restrict__ scale, const float* __restrict__ shift,
                           int total4) {
    int i4 = blockIdx.x * blockDim.x + threadIdx.x;
    if (i4 >= total4) return;
    long idx = (long)i4 * 4;
    ushort2 p0 = *(const ushort2*)(op + idx);
    ushort2 p1 = *(const ushort2*)(op + idx + 2);
    int c = (int)(idx & (D_HID - 1));
    float4 v;
    v.x = bf2f(p0.x) * scale[c + 0] + shift[c + 0];
    v.y = bf2f(p0.y) * scale[c + 1] + shift[c + 1];
    v.z = bf2f(p1.x) * scale[c + 2] + shift[c + 2];
    v.w = bf2f(p1.y) * scale[c + 3] + shift[c + 3];
    *(float4*)(out + idx) = v;
}

extern "C" void kernel_launch(void* const* d_in, const int* in_sizes, int n_in,
                              void* d_out, int out_size, void* d_ws, size_t ws_size,
                              hipStream_t stream) {
    const float* xs     = (const float*)d_in[0];
    const int*   eidx   = (const int*)d_in[1];
    const float* W_gcn  = (const float*)d_in[2];
    const float* b_gcn  = (const float*)d_in[3];
    const float* W_lin  = (const float*)d_in[4];
    const float* b_lin  = (const float*)d_in[5];
    const float* W_gate = (const float*)d_in[6];
    const float* b_gate = (const float*)d_in[7];
    const float* gamma  = (const float*)d_in[8];
    const float* beta   = (const float*)d_in[9];
    float* out = (float*)d_out;

    const int n = in_sizes[0] / D_IN;   // 50000
    const int E = in_sizes[1] / 2;      // 800000
    const int npad = (n + 63) & ~63;

    // workspace layout (512B aligned)
    char* ws = (char*)d_ws;
    size_t off = 0;
    auto alloc = [&](size_t bytes) {
        char* p = ws + off;
        off += (bytes + 511) & ~(size_t)511;
        return p;
    };
    int*            cnt      = (int*)alloc((size_t)n * 4);
    int*            part     = (int*)alloc((size_t)n * 4);
    int*            bsum     = (int*)alloc(1024);
    int*            offs     = (int*)alloc((size_t)n * 4);
    int*            cursor   = (int*)alloc((size_t)n * 4);
    int*            csr_src  = (int*)alloc((size_t)E * 4);
    float*          dinv     = (float*)alloc((size_t)n * 4);
    unsigned short* xscaled  = (unsigned short*)alloc((size_t)n * D_IN * 2);
    unsigned short* xs_bf    = (unsigned short*)alloc((size_t)npad * D_IN * 2);
    unsigned short* agg_bf   = (unsigned short*)alloc((size_t)npad * D_IN * 2);
    unsigned short* out_pre  = (unsigned short*)alloc((size_t)npad * D_HID * 2);
    unsigned short* Wt_gcn   = (unsigned short*)alloc((size_t)D_IN * D_HID * 2);
    unsigned short* Wt_lin   = (unsigned short*)alloc((size_t)D_IN * D_HID * 2);
    unsigned short* Wt_gate  = (unsigned short*)alloc((size_t)D_HID * D_HID * 2);
    float*          colsum   = (float*)alloc(D_HID * 4);
    float*          colsumsq = (float*)alloc(D_HID * 4);
    float*          scale    = (float*)alloc(D_HID * 4);
    float*          shift    = (float*)alloc(D_HID * 4);
    (void)ws_size;

    const int B = 256;
    const int nb = (n + 255) / 256;

    // 1. zero counters + BN accumulators
    k_init<<<(n + B - 1) / B, B, 0, stream>>>(cnt, colsum, colsumsq, n);
    // 1b. weights -> bf16 transposed
    k_wconv<<<(D_IN * D_HID + B - 1) / B, B, 0, stream>>>(W_gcn, Wt_gcn, D_IN, D_HID);
    k_wconv<<<(D_IN * D_HID + B - 1) / B, B, 0, stream>>>(W_lin, Wt_lin, D_IN, D_HID);
    k_wconv<<<(D_HID * D_HID + B - 1) / B, B, 0, stream>>>(W_gate, Wt_gate, D_HID, D_HID);
    // 2. count in-edges per node
    k_count<<<(E + B - 1) / B, B, 0, stream>>>(eidx, cnt, E);
    // 3. exclusive scan -> offsets, init cursors
    k_scan1<<<nb, 256, 0, stream>>>(cnt, part, bsum, n);
    k_scan2<<<1, 256, 0, stream>>>(bsum, nb);
    k_scan3<<<nb, 256, 0, stream>>>(part, bsum, offs, cursor, n);
    // 4. scatter edges to CSR-by-dst
    k_scatter<<<(E + B - 1) / B, B, 0, stream>>>(eidx, cursor, csr_src, E);
    // 5. dinv + bf16 features
    k_prep<<<(n * D_IN + B - 1) / B, B, 0, stream>>>(xs, cnt, dinv, xscaled, xs_bf, n);
    // 6. gather aggregation (wave per node), bf16 in/out
    k_gather<<<(n + 3) / 4, B, 0, stream>>>(csr_src, offs, cnt, xscaled, dinv, agg_bf, n);
    // 7. fused z-GEMM + gate-GEMM + lin-GEMM + epilogue + BN partials
    k_fused<<<npad / 64, B, 0, stream>>>(agg_bf, xs_bf, Wt_gcn, Wt_lin, Wt_gate,
                                         b_gcn, b_gate, b_lin, out_pre, colsum, colsumsq, n);
    // 8. BN finalize
    k_bn_final<<<1, D_HID, 0, stream>>>(colsum, colsumsq, gamma, beta, scale, shift, n);
    // 9. BN apply (bf16 -> fp32)
    {
        int total4 = n * D_HID / 4;
        k_bn_apply<<<(total4 + B - 1) / B, B, 0, stream>>>(out_pre, out, scale, shift, total4);
    }
}

// Round 5
// 299.201 us; speedup vs baseline: 3.4193x; 1.0523x over previous
//
#include <hip/hip_runtime.h>
#include <math.h>

#define NN 50000
#define NE 800000
#define D_IN 64
#define D_HID 256
#define BN_EPS 1e-5f
#define ZSTR 264   // z-tile LDS row stride in shorts (+8 pad: 16B-aligned rows, spread banks)

typedef __attribute__((ext_vector_type(8))) short short8;
typedef __attribute__((ext_vector_type(4))) float f32x4;

static __device__ __forceinline__ unsigned short f2bf(float f) {
    unsigned int u = __builtin_bit_cast(unsigned int, f);
    u += 0x7FFFu + ((u >> 16) & 1u);   // round-to-nearest-even
    return (unsigned short)(u >> 16);
}
static __device__ __forceinline__ float bf2f(unsigned short s) {
    unsigned int u = ((unsigned int)s) << 16;
    return __builtin_bit_cast(float, u);
}
// fast sigmoid: rcp(1+e^-x). x->+inf: exp->0 -> 1; x->-inf: exp->inf -> rcp(inf)=0. No NaN.
static __device__ __forceinline__ float fast_sigmoid(float x) {
    return __builtin_amdgcn_rcpf(1.0f + __expf(-x));
}
// fast tanh: 1 - 2*rcp(e^{2x}+1). x->+inf: 1-0=1; x->-inf: 1-2=-1. No NaN.
static __device__ __forceinline__ float fast_tanh(float x) {
    return 1.0f - 2.0f * __builtin_amdgcn_rcpf(__expf(2.0f * x) + 1.0f);
}

// ---------------- init: zero edge counters + BN accumulators ----------------
__global__ void k_init(int* __restrict__ cnt, float* __restrict__ colsum,
                       float* __restrict__ colsumsq, int n) {
    int i = blockIdx.x * blockDim.x + threadIdx.x;
    if (i < n) cnt[i] = 0;
    if (i < D_HID) { colsum[i] = 0.f; colsumsq[i] = 0.f; }
}

// ---------------- pack all three weights into MFMA B-frag-linear bf16 layout ----------------
// Bp[((ct*KC + kc)*64 + lane)*8 + j] = W[(kc*32 + (lane>>4)*8 + j)*256 + ct*16 + (lane&15)]
// => in-kernel frag load is base + lane*16B, fully coalesced.
__global__ void k_wpack(const float* __restrict__ W_gcn, const float* __restrict__ W_lin,
                        const float* __restrict__ W_gate,
                        unsigned short* __restrict__ Wp_gcn, unsigned short* __restrict__ Wp_lin,
                        unsigned short* __restrict__ Wp_gate) {
    int idx = blockIdx.x * blockDim.x + threadIdx.x;  // 98304 total
    const float* W;
    unsigned short* Wp;
    int KC, o;
    if (idx < 16384)            { W = W_gcn;  Wp = Wp_gcn;  KC = 2; o = idx; }
    else if (idx < 32768)       { W = W_lin;  Wp = Wp_lin;  KC = 2; o = idx - 16384; }
    else if (idx < 98304)       { W = W_gate; Wp = Wp_gate; KC = 8; o = idx - 32768; }
    else return;
    int j = o & 7;
    int lane = (o >> 3) & 63;
    int rest = o >> 9;
    int kc = rest % KC;
    int ct = rest / KC;
    int col = ct * 16 + (lane & 15);
    int k = kc * 32 + (lane >> 4) * 8 + j;
    Wp[o] = f2bf(W[k * D_HID + col]);
}

// ---------------- count in-edges per dst ----------------
__global__ void k_count(const int* __restrict__ eidx, int* __restrict__ cnt, int E) {
    int e = blockIdx.x * blockDim.x + threadIdx.x;
    if (e < E) atomicAdd(&cnt[eidx[E + e]], 1);
}

// ---------------- 2-level exclusive scan over cnt[n] ----------------
__global__ void k_scan1(const int* __restrict__ cnt, int* __restrict__ part,
                        int* __restrict__ bsum, int n) {
    __shared__ int s[256];
    int t = threadIdx.x;
    int i = blockIdx.x * 256 + t;
    int v = (i < n) ? cnt[i] : 0;
    s[t] = v;
    __syncthreads();
    for (int d = 1; d < 256; d <<= 1) {
        int t2 = (t >= d) ? s[t - d] : 0;
        __syncthreads();
        s[t] += t2;
        __syncthreads();
    }
    if (i < n) part[i] = s[t] - v;
    if (t == 255) bsum[blockIdx.x] = s[255];
}

__global__ void k_scan2(int* __restrict__ bsum, int nb) {
    __shared__ int s[256];
    int t = threadIdx.x;
    int v = (t < nb) ? bsum[t] : 0;
    s[t] = v;
    __syncthreads();
    for (int d = 1; d < 256; d <<= 1) {
        int t2 = (t >= d) ? s[t - d] : 0;
        __syncthreads();
        s[t] += t2;
        __syncthreads();
    }
    if (t < nb) bsum[t] = s[t] - v;
}

__global__ void k_scan3(const int* __restrict__ part, const int* __restrict__ bsum,
                        int* __restrict__ offs, int* __restrict__ cursor, int n) {
    int i = blockIdx.x * 256 + threadIdx.x;
    if (i < n) {
        int o = part[i] + bsum[blockIdx.x];
        offs[i] = o;
        cursor[i] = o;
    }
}

// ---------------- scatter edges into CSR-by-dst order ----------------
__global__ void k_scatter(const int* __restrict__ eidx, int* __restrict__ cursor,
                          int* __restrict__ csr_src, int E) {
    int e = blockIdx.x * blockDim.x + threadIdx.x;
    if (e >= E) return;
    int s = eidx[e];
    int d = eidx[E + e];
    int pos = atomicAdd(&cursor[d], 1);
    csr_src[pos] = s;
}

// A-frag-linear address for element (row i, feature k):
// ((i>>4)*KC + (k>>5))*512 + (((k>>3)&3)*16 + (i&15))*8 + (k&7)   [KC = D_IN/32 = 2]
static __device__ __forceinline__ long a_addr(int i, int k) {
    return ((long)((i >> 4) * 2 + (k >> 5)) << 9) + ((((k >> 3) & 3) * 16 + (i & 15)) << 3) + (k & 7);
}

// ---------------- dinv + bf16 features: xscaled row-major, xs_p frag-linear ----------------
__global__ void k_prep(const float* __restrict__ xs, const int* __restrict__ cnt,
                       float* __restrict__ dinv, unsigned short* __restrict__ xscaled,
                       unsigned short* __restrict__ xs_p, int n) {
    int idx = blockIdx.x * blockDim.x + threadIdx.x;  // over n*64
    if (idx >= n * D_IN) return;
    int i = idx >> 6;
    int k = idx & 63;
    float dv = rsqrtf(1.0f + (float)cnt[i]);
    float x = xs[idx];
    xscaled[idx] = f2bf(x * dv);
    xs_p[a_addr(i, k)] = f2bf(x);
    if (k == 0) dinv[i] = dv;
}

// ---------------- gather aggregation: wave per node, lane per feature ----------------
// agg_p[frag(i,k)] = bf16( dinv[i] * ( xscaled[i,k] + sum_{src in N(i)} xscaled[src,k] ) )
__global__ __launch_bounds__(256) void k_gather(const int* __restrict__ csr_src,
                                                const int* __restrict__ offs,
                                                const int* __restrict__ cnt,
                                                const unsigned short* __restrict__ xscaled,
                                                const float* __restrict__ dinv,
                                                unsigned short* __restrict__ agg_p, int n) {
    int wv = threadIdx.x >> 6;
    int lane = threadIdx.x & 63;
    int i = blockIdx.x * 4 + wv;
    if (i >= n) return;
    int start = offs[i];
    int c = cnt[i];
    float acc = bf2f(xscaled[(long)i * D_IN + lane]);  // self loop (pre-scaled)
    for (int base = 0; base < c; base += 64) {
        int m = c - base;
        m = m < 64 ? m : 64;
        int idx = (lane < m) ? csr_src[start + base + lane] : 0;
        int j = 0;
        for (; j + 8 <= m; j += 8) {
            int s0 = __shfl(idx, j + 0);
            int s1 = __shfl(idx, j + 1);
            int s2 = __shfl(idx, j + 2);
            int s3 = __shfl(idx, j + 3);
            int s4 = __shfl(idx, j + 4);
            int s5 = __shfl(idx, j + 5);
            int s6 = __shfl(idx, j + 6);
            int s7 = __shfl(idx, j + 7);
            float v0 = bf2f(xscaled[(long)s0 * D_IN + lane]);
            float v1 = bf2f(xscaled[(long)s1 * D_IN + lane]);
            float v2 = bf2f(xscaled[(long)s2 * D_IN + lane]);
            float v3 = bf2f(xscaled[(long)s3 * D_IN + lane]);
            float v4 = bf2f(xscaled[(long)s4 * D_IN + lane]);
            float v5 = bf2f(xscaled[(long)s5 * D_IN + lane]);
            float v6 = bf2f(xscaled[(long)s6 * D_IN + lane]);
            float v7 = bf2f(xscaled[(long)s7 * D_IN + lane]);
            acc += ((v0 + v1) + (v2 + v3)) + ((v4 + v5) + (v6 + v7));
        }
        for (; j < m; j++) {
            int s0 = __shfl(idx, j);
            acc += bf2f(xscaled[(long)s0 * D_IN + lane]);
        }
    }
    agg_p[a_addr(i, lane)] = f2bf(acc * dinv[i]);
}

// ---------------- fused: z GEMM -> LDS -> gate+lin GEMMs -> epilogue -> coalesced store ----
// block = 64 rows x 256 cols, 4 waves; wave wv owns cols [wv*64, wv*64+64)
__global__ __launch_bounds__(256) void k_fused(const unsigned short* __restrict__ agg_p,
                                               const unsigned short* __restrict__ xs_p,
                                               const unsigned short* __restrict__ Wp_gcn,
                                               const unsigned short* __restrict__ Wp_lin,
                                               const unsigned short* __restrict__ Wp_gate,
                                               const float* __restrict__ b_gcn,
                                               const float* __restrict__ bg,
                                               const float* __restrict__ bl,
                                               unsigned short* __restrict__ out_pre,  // [npad][256]
                                               float* __restrict__ colsum,
                                               float* __restrict__ colsumsq, int n) {
    __shared__ unsigned short z_lds[64 * ZSTR];   // 33.8 KB

    int tid = threadIdx.x;
    int wv = tid >> 6;
    int lane = tid & 63;
    int l15 = lane & 15;
    int quad = lane >> 4;
    int row0 = blockIdx.x * 64;
    int rt0 = row0 >> 4;

    // ---- phase A: z = tanh(agg @ W_gcn + b_gcn), K=64, all frag loads lane-coalesced ----
    {
        f32x4 accz[4][4];
#pragma unroll
        for (int a = 0; a < 4; a++)
#pragma unroll
            for (int c = 0; c < 4; c++) accz[a][c] = (f32x4){0.f, 0.f, 0.f, 0.f};
#pragma unroll
        for (int kc = 0; kc < 2; kc++) {
            short8 af[4];
#pragma unroll
            for (int tm = 0; tm < 4; tm++)
                af[tm] = *(const short8*)(agg_p + ((long)((rt0 + tm) * 2 + kc) << 9) + lane * 8);
            short8 bfr[4];
#pragma unroll
            for (int tn = 0; tn < 4; tn++)
                bfr[tn] = *(const short8*)(Wp_gcn + ((long)((wv * 4 + tn) * 2 + kc) << 9) + lane * 8);
#pragma unroll
            for (int tm = 0; tm < 4; tm++)
#pragma unroll
                for (int tn = 0; tn < 4; tn++)
                    accz[tm][tn] = __builtin_amdgcn_mfma_f32_16x16x32_bf16(af[tm], bfr[tn], accz[tm][tn], 0, 0, 0);
        }
#pragma unroll
        for (int tn = 0; tn < 4; tn++) {
            int col = wv * 64 + tn * 16 + l15;
            float bias = b_gcn[col];
#pragma unroll
            for (int tm = 0; tm < 4; tm++)
#pragma unroll
                for (int r2 = 0; r2 < 4; r2++) {
                    int rl = tm * 16 + quad * 4 + r2;
                    z_lds[rl * ZSTR + col] = f2bf(fast_tanh(accz[tm][tn][r2] + bias));
                }
        }
    }
    __syncthreads();

    // ---- phase B1: xl = xs @ W_lin, K=64 ----
    f32x4 acc2[4][4];
#pragma unroll
    for (int a = 0; a < 4; a++)
#pragma unroll
        for (int c = 0; c < 4; c++) acc2[a][c] = (f32x4){0.f, 0.f, 0.f, 0.f};
#pragma unroll
    for (int kc = 0; kc < 2; kc++) {
        short8 af[4];
#pragma unroll
        for (int tm = 0; tm < 4; tm++)
            af[tm] = *(const short8*)(xs_p + ((long)((rt0 + tm) * 2 + kc) << 9) + lane * 8);
        short8 bfr[4];
#pragma unroll
        for (int tn = 0; tn < 4; tn++)
            bfr[tn] = *(const short8*)(Wp_lin + ((long)((wv * 4 + tn) * 2 + kc) << 9) + lane * 8);
#pragma unroll
        for (int tm = 0; tm < 4; tm++)
#pragma unroll
            for (int tn = 0; tn < 4; tn++)
                acc2[tm][tn] = __builtin_amdgcn_mfma_f32_16x16x32_bf16(af[tm], bfr[tn], acc2[tm][tn], 0, 0, 0);
    }

    // ---- phase B2: logits = z @ W_gate, K=256, A from LDS, B lane-coalesced ----
    f32x4 acc1[4][4];
#pragma unroll
    for (int a = 0; a < 4; a++)
#pragma unroll
        for (int c = 0; c < 4; c++) acc1[a][c] = (f32x4){0.f, 0.f, 0.f, 0.f};
#pragma unroll
    for (int kc = 0; kc < 8; kc++) {
        short8 af[4];
#pragma unroll
        for (int tm = 0; tm < 4; tm++)
            af[tm] = *(const short8*)(&z_lds[(tm * 16 + l15) * ZSTR + kc * 32 + quad * 8]);
        short8 bfr[4];
#pragma unroll
        for (int tn = 0; tn < 4; tn++)
            bfr[tn] = *(const short8*)(Wp_gate + ((long)((wv * 4 + tn) * 8 + kc) << 9) + lane * 8);
#pragma unroll
        for (int tm = 0; tm < 4; tm++)
#pragma unroll
            for (int tn = 0; tn < 4; tn++)
                acc1[tm][tn] = __builtin_amdgcn_mfma_f32_16x16x32_bf16(af[tm], bfr[tn], acc1[tm][tn], 0, 0, 0);
    }
    __syncthreads();   // all B2 LDS reads done before in-place overwrite

    // ---- epilogue: o = relu((1-g)*xl + g*z); write o back into z_lds; BN partials ----
    float ls[4] = {0.f, 0.f, 0.f, 0.f};
    float lsq[4] = {0.f, 0.f, 0.f, 0.f};
#pragma unroll
    for (int tn = 0; tn < 4; tn++) {
        int col = wv * 64 + tn * 16 + l15;
        float bgc = bg[col];
        float blc = bl[col];
#pragma unroll
        for (int tm = 0; tm < 4; tm++)
#pragma unroll
            for (int r2 = 0; r2 < 4; r2++) {
                int rl = tm * 16 + quad * 4 + r2;
                int row = row0 + rl;
                if (row < n) {
                    float g = fast_sigmoid(acc1[tm][tn][r2] + bgc);
                    float zv = bf2f(z_lds[rl * ZSTR + col]);
                    float xv = acc2[tm][tn][r2] + blc;
                    float o = fmaxf((1.f - g) * xv + g * zv, 0.f);
                    z_lds[rl * ZSTR + col] = f2bf(o);
                    ls[tn] += o;
                    lsq[tn] += o * o;
                }
            }
    }
#pragma unroll
    for (int tn = 0; tn < 4; tn++) {
        float s = ls[tn];
        float q = lsq[tn];
        s += __shfl_xor(s, 16);
        s += __shfl_xor(s, 32);
        q += __shfl_xor(q, 16);
        q += __shfl_xor(q, 32);
        if (quad == 0) {
            int col = wv * 64 + tn * 16 + l15;
            atomicAdd(&colsum[col], s);
            atomicAdd(&colsumsq[col], q);
        }
    }
    __syncthreads();

    // ---- coalesced tile store: 8 x dwordx4 per thread ----
#pragma unroll
    for (int it = 0; it < 8; it++) {
        int g = it * 2048 + tid * 8;       // shorts within 64x256 tile
        int row = g >> 8;
        int col = g & 255;
        short8 v = *(const short8*)(&z_lds[row * ZSTR + col]);
        *(short8*)(out_pre + (long)(row0 + row) * D_HID + col) = v;
    }
}

// ---------------- BN finalize: per-column scale/shift ----------------
__global__ void k_bn_final(const float* __restrict__ colsum, const float* __restrict__ colsumsq,
                           const float* __restrict__ gamma, const float* __restrict__ beta,
                           float* __restrict__ scale, float* __restrict__ shift, int n) {
    int c = threadIdx.x;
    float inv_n = 1.0f / (float)n;
    float mu = colsum[c] * inv_n;
    float var = colsumsq[c] * inv_n - mu * mu;
    float sc = gamma[c] * rsqrtf(var + BN_EPS);
    scale[c] = sc;
    shift[c] = beta[c] - mu * sc;
}

// ---------------- BN apply: bf16 in -> fp32 out ----------------
__global__ void k_bn_apply(const unsigned short* __restrict__ op, float* __restrict__ out,
                           const float* __restrict__ scale, const float* __restrict__ shift,
                           int total4) {
    int i4 = blockIdx.x * blockDim.x + threadIdx.x;
    if (i4 >= total4) return;
    long idx = (long)i4 * 4;
    ushort2 p0 = *(const ushort2*)(op + idx);
    ushort2 p1 = *(const ushort2*)(op + idx + 2);
    int c = (int)(idx & (D_HID - 1));
    float4 v;
    v.x = bf2f(p0.x) * scale[c + 0] + shift[c + 0];
    v.y = bf2f(p0.y) * scale[c + 1] + shift[c + 1];
    v.z = bf2f(p1.x) * scale[c + 2] + shift[c + 2];
    v.w = bf2f(p1.y) * scale[c + 3] + shift[c + 3];
    *(float4*)(out + idx) = v;
}

extern "C" void kernel_launch(void* const* d_in, const int* in_sizes, int n_in,
                              void* d_out, int out_size, void* d_ws, size_t ws_size,
                              hipStream_t stream) {
    const float* xs     = (const float*)d_in[0];
    const int*   eidx   = (const int*)d_in[1];
    const float* W_gcn  = (const float*)d_in[2];
    const float* b_gcn  = (const float*)d_in[3];
    const float* W_lin  = (const float*)d_in[4];
    const float* b_lin  = (const float*)d_in[5];
    const float* W_gate = (const float*)d_in[6];
    const float* b_gate = (const float*)d_in[7];
    const float* gamma  = (const float*)d_in[8];
    const float* beta   = (const float*)d_in[9];
    float* out = (float*)d_out;

    const int n = in_sizes[0] / D_IN;   // 50000
    const int E = in_sizes[1] / 2;      // 800000
    const int npad = (n + 63) & ~63;

    // workspace layout (512B aligned)
    char* ws = (char*)d_ws;
    size_t off = 0;
    auto alloc = [&](size_t bytes) {
        char* p = ws + off;
        off += (bytes + 511) & ~(size_t)511;
        return p;
    };
    int*            cnt      = (int*)alloc((size_t)n * 4);
    int*            part     = (int*)alloc((size_t)n * 4);
    int*            bsum     = (int*)alloc(1024);
    int*            offs     = (int*)alloc((size_t)n * 4);
    int*            cursor   = (int*)alloc((size_t)n * 4);
    int*            csr_src  = (int*)alloc((size_t)E * 4);
    float*          dinv     = (float*)alloc((size_t)n * 4);
    unsigned short* xscaled  = (unsigned short*)alloc((size_t)n * D_IN * 2);
    unsigned short* xs_p     = (unsigned short*)alloc((size_t)npad * D_IN * 2);
    unsigned short* agg_p    = (unsigned short*)alloc((size_t)npad * D_IN * 2);
    unsigned short* out_pre  = (unsigned short*)alloc((size_t)npad * D_HID * 2);
    unsigned short* Wp_gcn   = (unsigned short*)alloc((size_t)D_IN * D_HID * 2);
    unsigned short* Wp_lin   = (unsigned short*)alloc((size_t)D_IN * D_HID * 2);
    unsigned short* Wp_gate  = (unsigned short*)alloc((size_t)D_HID * D_HID * 2);
    float*          colsum   = (float*)alloc(D_HID * 4);
    float*          colsumsq = (float*)alloc(D_HID * 4);
    float*          scale    = (float*)alloc(D_HID * 4);
    float*          shift    = (float*)alloc(D_HID * 4);
    (void)ws_size;

    const int B = 256;
    const int nb = (n + 255) / 256;

    // 1. zero counters + BN accumulators
    k_init<<<(n + B - 1) / B, B, 0, stream>>>(cnt, colsum, colsumsq, n);
    // 1b. all weights -> bf16 frag-linear packed
    k_wpack<<<(98304 + B - 1) / B, B, 0, stream>>>(W_gcn, W_lin, W_gate, Wp_gcn, Wp_lin, Wp_gate);
    // 2. count in-edges per node
    k_count<<<(E + B - 1) / B, B, 0, stream>>>(eidx, cnt, E);
    // 3. exclusive scan -> offsets, init cursors
    k_scan1<<<nb, 256, 0, stream>>>(cnt, part, bsum, n);
    k_scan2<<<1, 256, 0, stream>>>(bsum, nb);
    k_scan3<<<nb, 256, 0, stream>>>(part, bsum, offs, cursor, n);
    // 4. scatter edges to CSR-by-dst
    k_scatter<<<(E + B - 1) / B, B, 0, stream>>>(eidx, cursor, csr_src, E);
    // 5. dinv + bf16 features (xscaled row-major, xs_p frag-linear)
    k_prep<<<(n * D_IN + B - 1) / B, B, 0, stream>>>(xs, cnt, dinv, xscaled, xs_p, n);
    // 6. gather aggregation (wave per node) -> agg_p frag-linear
    k_gather<<<(n + 3) / 4, B, 0, stream>>>(csr_src, offs, cnt, xscaled, dinv, agg_p, n);
    // 7. fused z-GEMM + gate-GEMM + lin-GEMM + epilogue + BN partials
    k_fused<<<npad / 64, B, 0, stream>>>(agg_p, xs_p, Wp_gcn, Wp_lin, Wp_gate,
                                         b_gcn, b_gate, b_lin, out_pre, colsum, colsumsq, n);
    // 8. BN finalize
    k_bn_final<<<1, D_HID, 0, stream>>>(colsum, colsumsq, gamma, beta, scale, shift, n);
    // 9. BN apply (bf16 -> fp32)
    {
        int total4 = n * D_HID / 4;
        k_bn_apply<<<(total4 + B - 1) / B, B, 0, stream>>>(out_pre, out, scale, shift, total4);
    }
}

// Round 6
// 298.854 us; speedup vs baseline: 3.4233x; 1.0012x over previous
//
#include <hip/hip_runtime.h>
#include <math.h>

#define NN 50000
#define NE 800000
#define D_IN 64
#define D_HID 256
#define BN_EPS 1e-5f
#define ZSTR 264   // z-tile LDS row stride in shorts (+8 pad: 16B-aligned rows, spread banks)

typedef __attribute__((ext_vector_type(8))) short short8;
typedef __attribute__((ext_vector_type(4))) float f32x4;

static __device__ __forceinline__ unsigned short f2bf(float f) {
    unsigned int u = __builtin_bit_cast(unsigned int, f);
    u += 0x7FFFu + ((u >> 16) & 1u);   // round-to-nearest-even
    return (unsigned short)(u >> 16);
}
static __device__ __forceinline__ float bf2f(unsigned short s) {
    unsigned int u = ((unsigned int)s) << 16;
    return __builtin_bit_cast(float, u);
}
// fast sigmoid: rcp(1+e^-x). Saturates cleanly at +/-inf, no NaN.
static __device__ __forceinline__ float fast_sigmoid(float x) {
    return __builtin_amdgcn_rcpf(1.0f + __expf(-x));
}
// fast tanh: 1 - 2*rcp(e^{2x}+1). Saturates cleanly, no NaN.
static __device__ __forceinline__ float fast_tanh(float x) {
    return 1.0f - 2.0f * __builtin_amdgcn_rcpf(__expf(2.0f * x) + 1.0f);
}

// ---------------- setup: zero counters/BN accums + pack all weights (one launch) ----------
// Wp[((ct*KC + kc)*64 + lane)*8 + j] = W[(kc*32 + (lane>>4)*8 + j)*256 + ct*16 + (lane&15)]
__global__ void k_setup(const float* __restrict__ W_gcn, const float* __restrict__ W_lin,
                        const float* __restrict__ W_gate,
                        unsigned short* __restrict__ Wp_gcn, unsigned short* __restrict__ Wp_lin,
                        unsigned short* __restrict__ Wp_gate,
                        int* __restrict__ cnt, float* __restrict__ colsum,
                        float* __restrict__ colsumsq, int n) {
    int idx = blockIdx.x * blockDim.x + threadIdx.x;
    if (idx < n) cnt[idx] = 0;
    if (idx < D_HID) { colsum[idx] = 0.f; colsumsq[idx] = 0.f; }
    if (idx >= 98304) return;
    const float* W;
    unsigned short* Wp;
    int KC, o;
    if (idx < 16384)      { W = W_gcn;  Wp = Wp_gcn;  KC = 2; o = idx; }
    else if (idx < 32768) { W = W_lin;  Wp = Wp_lin;  KC = 2; o = idx - 16384; }
    else                  { W = W_gate; Wp = Wp_gate; KC = 8; o = idx - 32768; }
    int j = o & 7;
    int lane = (o >> 3) & 63;
    int rest = o >> 9;
    int kc = rest % KC;
    int ct = rest / KC;
    int col = ct * 16 + (lane & 15);
    int k = kc * 32 + (lane >> 4) * 8 + j;
    Wp[o] = f2bf(W[k * D_HID + col]);
}

// ---------------- count in-edges per dst ----------------
__global__ void k_count(const int* __restrict__ eidx, int* __restrict__ cnt, int E) {
    int e = blockIdx.x * blockDim.x + threadIdx.x;
    if (e < E) atomicAdd(&cnt[eidx[E + e]], 1);
}

// ---------------- 2-level exclusive scan over cnt[n] ----------------
__global__ void k_scan1(const int* __restrict__ cnt, int* __restrict__ part,
                        int* __restrict__ bsum, int n) {
    __shared__ int s[256];
    int t = threadIdx.x;
    int i = blockIdx.x * 256 + t;
    int v = (i < n) ? cnt[i] : 0;
    s[t] = v;
    __syncthreads();
    for (int d = 1; d < 256; d <<= 1) {
        int t2 = (t >= d) ? s[t - d] : 0;
        __syncthreads();
        s[t] += t2;
        __syncthreads();
    }
    if (i < n) part[i] = s[t] - v;
    if (t == 255) bsum[blockIdx.x] = s[255];
}

__global__ void k_scan2(int* __restrict__ bsum, int nb) {
    __shared__ int s[256];
    int t = threadIdx.x;
    int v = (t < nb) ? bsum[t] : 0;
    s[t] = v;
    __syncthreads();
    for (int d = 1; d < 256; d <<= 1) {
        int t2 = (t >= d) ? s[t - d] : 0;
        __syncthreads();
        s[t] += t2;
        __syncthreads();
    }
    if (t < nb) bsum[t] = s[t] - v;
}

__global__ void k_scan3(const int* __restrict__ part, const int* __restrict__ bsum,
                        int* __restrict__ offs, int* __restrict__ cursor, int n) {
    int i = blockIdx.x * 256 + threadIdx.x;
    if (i < n) {
        int o = part[i] + bsum[blockIdx.x];
        offs[i] = o;
        cursor[i] = o;
    }
}

// ---------------- scatter edges into CSR-by-dst order ----------------
__global__ void k_scatter(const int* __restrict__ eidx, int* __restrict__ cursor,
                          int* __restrict__ csr_src, int E) {
    int e = blockIdx.x * blockDim.x + threadIdx.x;
    if (e >= E) return;
    int s = eidx[e];
    int d = eidx[E + e];
    int pos = atomicAdd(&cursor[d], 1);
    csr_src[pos] = s;
}

// A-frag-linear address for element (row i, feature k):
// ((i>>4)*2 + (k>>5))*512 + (((k>>3)&3)*16 + (i&15))*8 + (k&7)
static __device__ __forceinline__ long a_addr(int i, int k) {
    return ((long)((i >> 4) * 2 + (k >> 5)) << 9) + ((((k >> 3) & 3) * 16 + (i & 15)) << 3) + (k & 7);
}

// ---------------- dinv + bf16 features: xscaled row-major, xs_p frag-linear ----------------
__global__ void k_prep(const float* __restrict__ xs, const int* __restrict__ cnt,
                       float* __restrict__ dinv, unsigned short* __restrict__ xscaled,
                       unsigned short* __restrict__ xs_p, int n) {
    int idx = blockIdx.x * blockDim.x + threadIdx.x;  // over n*64
    if (idx >= n * D_IN) return;
    int i = idx >> 6;
    int k = idx & 63;
    float dv = rsqrtf(1.0f + (float)cnt[i]);
    float x = xs[idx];
    xscaled[idx] = f2bf(x * dv);
    xs_p[a_addr(i, k)] = f2bf(x);
    if (k == 0) dinv[i] = dv;
}

// ---------------- gather aggregation: wave per node, lane per feature ----------------
__global__ __launch_bounds__(256) void k_gather(const int* __restrict__ csr_src,
                                                const int* __restrict__ offs,
                                                const int* __restrict__ cnt,
                                                const unsigned short* __restrict__ xscaled,
                                                const float* __restrict__ dinv,
                                                unsigned short* __restrict__ agg_p, int n) {
    int wv = threadIdx.x >> 6;
    int lane = threadIdx.x & 63;
    int i = blockIdx.x * 4 + wv;
    if (i >= n) return;
    int start = offs[i];
    int c = cnt[i];
    float acc = bf2f(xscaled[(long)i * D_IN + lane]);  // self loop (pre-scaled)
    for (int base = 0; base < c; base += 64) {
        int m = c - base;
        m = m < 64 ? m : 64;
        int idx = (lane < m) ? csr_src[start + base + lane] : 0;
        int j = 0;
        for (; j + 8 <= m; j += 8) {
            int s0 = __shfl(idx, j + 0);
            int s1 = __shfl(idx, j + 1);
            int s2 = __shfl(idx, j + 2);
            int s3 = __shfl(idx, j + 3);
            int s4 = __shfl(idx, j + 4);
            int s5 = __shfl(idx, j + 5);
            int s6 = __shfl(idx, j + 6);
            int s7 = __shfl(idx, j + 7);
            float v0 = bf2f(xscaled[(long)s0 * D_IN + lane]);
            float v1 = bf2f(xscaled[(long)s1 * D_IN + lane]);
            float v2 = bf2f(xscaled[(long)s2 * D_IN + lane]);
            float v3 = bf2f(xscaled[(long)s3 * D_IN + lane]);
            float v4 = bf2f(xscaled[(long)s4 * D_IN + lane]);
            float v5 = bf2f(xscaled[(long)s5 * D_IN + lane]);
            float v6 = bf2f(xscaled[(long)s6 * D_IN + lane]);
            float v7 = bf2f(xscaled[(long)s7 * D_IN + lane]);
            acc += ((v0 + v1) + (v2 + v3)) + ((v4 + v5) + (v6 + v7));
        }
        for (; j < m; j++) {
            int s0 = __shfl(idx, j);
            acc += bf2f(xscaled[(long)s0 * D_IN + lane]);
        }
    }
    agg_p[a_addr(i, lane)] = f2bf(acc * dinv[i]);
}

// ---------------- fused: z GEMM -> LDS -> gate+lin GEMMs -> epilogue -> coalesced store ----
// block = 64 rows x 256 cols, 4 waves; wave wv owns cols [wv*64, wv*64+64)
// __launch_bounds__(256,4): pin VGPR <= 128 (occupancy halves past 128 — round-5 regression)
__global__ __launch_bounds__(256, 4) void k_fused(const unsigned short* __restrict__ agg_p,
                                               const unsigned short* __restrict__ xs_p,
                                               const unsigned short* __restrict__ Wp_gcn,
                                               const unsigned short* __restrict__ Wp_lin,
                                               const unsigned short* __restrict__ Wp_gate,
                                               const float* __restrict__ b_gcn,
                                               const float* __restrict__ bg,
                                               const float* __restrict__ bl,
                                               unsigned short* __restrict__ out_pre,  // [npad][256]
                                               float* __restrict__ colsum,
                                               float* __restrict__ colsumsq, int n) {
    __shared__ unsigned short z_lds[64 * ZSTR];   // 33.8 KB

    int tid = threadIdx.x;
    int wv = tid >> 6;
    int lane = tid & 63;
    int l15 = lane & 15;
    int quad = lane >> 4;
    int row0 = blockIdx.x * 64;
    int rt0 = row0 >> 4;

    // ---- phase A: z = tanh(agg @ W_gcn + b_gcn), K=64, frag loads lane-coalesced ----
    {
        f32x4 accz[4][4];
#pragma unroll
        for (int a = 0; a < 4; a++)
#pragma unroll
            for (int c = 0; c < 4; c++) accz[a][c] = (f32x4){0.f, 0.f, 0.f, 0.f};
#pragma unroll
        for (int kc = 0; kc < 2; kc++) {
            short8 af[4];
#pragma unroll
            for (int tm = 0; tm < 4; tm++)
                af[tm] = *(const short8*)(agg_p + ((long)((rt0 + tm) * 2 + kc) << 9) + lane * 8);
            short8 bfr[4];
#pragma unroll
            for (int tn = 0; tn < 4; tn++)
                bfr[tn] = *(const short8*)(Wp_gcn + ((long)((wv * 4 + tn) * 2 + kc) << 9) + lane * 8);
#pragma unroll
            for (int tm = 0; tm < 4; tm++)
#pragma unroll
                for (int tn = 0; tn < 4; tn++)
                    accz[tm][tn] = __builtin_amdgcn_mfma_f32_16x16x32_bf16(af[tm], bfr[tn], accz[tm][tn], 0, 0, 0);
        }
#pragma unroll
        for (int tn = 0; tn < 4; tn++) {
            int col = wv * 64 + tn * 16 + l15;
            float bias = b_gcn[col];
#pragma unroll
            for (int tm = 0; tm < 4; tm++)
#pragma unroll
                for (int r2 = 0; r2 < 4; r2++) {
                    int rl = tm * 16 + quad * 4 + r2;
                    z_lds[rl * ZSTR + col] = f2bf(fast_tanh(accz[tm][tn][r2] + bias));
                }
        }
    }
    __syncthreads();

    // ---- phase B1: xl = xs @ W_lin, K=64 ----
    f32x4 acc2[4][4];
#pragma unroll
    for (int a = 0; a < 4; a++)
#pragma unroll
        for (int c = 0; c < 4; c++) acc2[a][c] = (f32x4){0.f, 0.f, 0.f, 0.f};
#pragma unroll
    for (int kc = 0; kc < 2; kc++) {
        short8 af[4];
#pragma unroll
        for (int tm = 0; tm < 4; tm++)
            af[tm] = *(const short8*)(xs_p + ((long)((rt0 + tm) * 2 + kc) << 9) + lane * 8);
        short8 bfr[4];
#pragma unroll
        for (int tn = 0; tn < 4; tn++)
            bfr[tn] = *(const short8*)(Wp_lin + ((long)((wv * 4 + tn) * 2 + kc) << 9) + lane * 8);
#pragma unroll
        for (int tm = 0; tm < 4; tm++)
#pragma unroll
            for (int tn = 0; tn < 4; tn++)
                acc2[tm][tn] = __builtin_amdgcn_mfma_f32_16x16x32_bf16(af[tm], bfr[tn], acc2[tm][tn], 0, 0, 0);
    }

    // ---- phase B2: logits = z @ W_gate, K=256, A from LDS, B lane-coalesced ----
    f32x4 acc1[4][4];
#pragma unroll
    for (int a = 0; a < 4; a++)
#pragma unroll
        for (int c = 0; c < 4; c++) acc1[a][c] = (f32x4){0.f, 0.f, 0.f, 0.f};
#pragma unroll
    for (int kc = 0; kc < 8; kc++) {
        short8 af[4];
#pragma unroll
        for (int tm = 0; tm < 4; tm++)
            af[tm] = *(const short8*)(&z_lds[(tm * 16 + l15) * ZSTR + kc * 32 + quad * 8]);
        short8 bfr[4];
#pragma unroll
        for (int tn = 0; tn < 4; tn++)
            bfr[tn] = *(const short8*)(Wp_gate + ((long)((wv * 4 + tn) * 8 + kc) << 9) + lane * 8);
#pragma unroll
        for (int tm = 0; tm < 4; tm++)
#pragma unroll
            for (int tn = 0; tn < 4; tn++)
                acc1[tm][tn] = __builtin_amdgcn_mfma_f32_16x16x32_bf16(af[tm], bfr[tn], acc1[tm][tn], 0, 0, 0);
    }
    __syncthreads();   // all B2 LDS reads done before in-place overwrite

    // ---- epilogue: o = relu((1-g)*xl + g*z); write o back into z_lds; BN partials ----
    float ls[4] = {0.f, 0.f, 0.f, 0.f};
    float lsq[4] = {0.f, 0.f, 0.f, 0.f};
#pragma unroll
    for (int tn = 0; tn < 4; tn++) {
        int col = wv * 64 + tn * 16 + l15;
        float bgc = bg[col];
        float blc = bl[col];
#pragma unroll
        for (int tm = 0; tm < 4; tm++)
#pragma unroll
            for (int r2 = 0; r2 < 4; r2++) {
                int rl = tm * 16 + quad * 4 + r2;
                int row = row0 + rl;
                if (row < n) {
                    float g = fast_sigmoid(acc1[tm][tn][r2] + bgc);
                    float zv = bf2f(z_lds[rl * ZSTR + col]);
                    float xv = acc2[tm][tn][r2] + blc;
                    float o = fmaxf((1.f - g) * xv + g * zv, 0.f);
                    z_lds[rl * ZSTR + col] = f2bf(o);
                    ls[tn] += o;
                    lsq[tn] += o * o;
                }
            }
    }
    __syncthreads();

    // ---- coalesced tile store: 8 x dwordx4 per thread ----
#pragma unroll
    for (int it = 0; it < 8; it++) {
        int g = it * 2048 + tid * 8;       // shorts within 64x256 tile
        int row = g >> 8;
        int col = g & 255;
        short8 v = *(const short8*)(&z_lds[row * ZSTR + col]);
        *(short8*)(out_pre + (long)(row0 + row) * D_HID + col) = v;
    }

    // ---- BN partial atomics last (lets the tile store drain first) ----
#pragma unroll
    for (int tn = 0; tn < 4; tn++) {
        float s = ls[tn];
        float q = lsq[tn];
        s += __shfl_xor(s, 16);
        s += __shfl_xor(s, 32);
        q += __shfl_xor(q, 16);
        q += __shfl_xor(q, 32);
        if (quad == 0) {
            int col = wv * 64 + tn * 16 + l15;
            atomicAdd(&colsum[col], s);
            atomicAdd(&colsumsq[col], q);
        }
    }
}

// ---------------- BN finalize: per-column scale/shift ----------------
__global__ void k_bn_final(const float* __restrict__ colsum, const float* __restrict__ colsumsq,
                           const float* __restrict__ gamma, const float* __restrict__ beta,
                           float* __restrict__ scale, float* __restrict__ shift, int n) {
    int c = threadIdx.x;
    float inv_n = 1.0f / (float)n;
    float mu = colsum[c] * inv_n;
    float var = colsumsq[c] * inv_n - mu * mu;
    float sc = gamma[c] * rsqrtf(var + BN_EPS);
    scale[c] = sc;
    shift[c] = beta[c] - mu * sc;
}

// ---------------- BN apply: bf16 in -> fp32 out ----------------
__global__ void k_bn_apply(const unsigned short* __restrict__ op, float* __restrict__ out,
                           const float* __restrict__ scale, const float* __restrict__ shift,
                           int total4) {
    int i4 = blockIdx.x * blockDim.x + threadIdx.x;
    if (i4 >= total4) return;
    long idx = (long)i4 * 4;
    ushort2 p0 = *(const ushort2*)(op + idx);
    ushort2 p1 = *(const ushort2*)(op + idx + 2);
    int c = (int)(idx & (D_HID - 1));
    float4 v;
    v.x = bf2f(p0.x) * scale[c + 0] + shift[c + 0];
    v.y = bf2f(p0.y) * scale[c + 1] + shift[c + 1];
    v.z = bf2f(p1.x) * scale[c + 2] + shift[c + 2];
    v.w = bf2f(p1.y) * scale[c + 3] + shift[c + 3];
    *(float4*)(out + idx) = v;
}

extern "C" void kernel_launch(void* const* d_in, const int* in_sizes, int n_in,
                              void* d_out, int out_size, void* d_ws, size_t ws_size,
                              hipStream_t stream) {
    const float* xs     = (const float*)d_in[0];
    const int*   eidx   = (const int*)d_in[1];
    const float* W_gcn  = (const float*)d_in[2];
    const float* b_gcn  = (const float*)d_in[3];
    const float* W_lin  = (const float*)d_in[4];
    const float* b_lin  = (const float*)d_in[5];
    const float* W_gate = (const float*)d_in[6];
    const float* b_gate = (const float*)d_in[7];
    const float* gamma  = (const float*)d_in[8];
    const float* beta   = (const float*)d_in[9];
    float* out = (float*)d_out;

    const int n = in_sizes[0] / D_IN;   // 50000
    const int E = in_sizes[1] / 2;      // 800000
    const int npad = (n + 63) & ~63;

    // workspace layout (512B aligned)
    char* ws = (char*)d_ws;
    size_t off = 0;
    auto alloc = [&](size_t bytes) {
        char* p = ws + off;
        off += (bytes + 511) & ~(size_t)511;
        return p;
    };
    int*            cnt      = (int*)alloc((size_t)n * 4);
    int*            part     = (int*)alloc((size_t)n * 4);
    int*            bsum     = (int*)alloc(1024);
    int*            offs     = (int*)alloc((size_t)n * 4);
    int*            cursor   = (int*)alloc((size_t)n * 4);
    int*            csr_src  = (int*)alloc((size_t)E * 4);
    float*          dinv     = (float*)alloc((size_t)n * 4);
    unsigned short* xscaled  = (unsigned short*)alloc((size_t)n * D_IN * 2);
    unsigned short* xs_p     = (unsigned short*)alloc((size_t)npad * D_IN * 2);
    unsigned short* agg_p    = (unsigned short*)alloc((size_t)npad * D_IN * 2);
    unsigned short* out_pre  = (unsigned short*)alloc((size_t)npad * D_HID * 2);
    unsigned short* Wp_gcn   = (unsigned short*)alloc((size_t)D_IN * D_HID * 2);
    unsigned short* Wp_lin   = (unsigned short*)alloc((size_t)D_IN * D_HID * 2);
    unsigned short* Wp_gate  = (unsigned short*)alloc((size_t)D_HID * D_HID * 2);
    float*          colsum   = (float*)alloc(D_HID * 4);
    float*          colsumsq = (float*)alloc(D_HID * 4);
    float*          scale    = (float*)alloc(D_HID * 4);
    float*          shift    = (float*)alloc(D_HID * 4);
    (void)ws_size;

    const int B = 256;
    const int nb = (n + 255) / 256;

    // 1. setup: zero counters/BN accums + pack weights (single launch)
    k_setup<<<(98304 + B - 1) / B, B, 0, stream>>>(W_gcn, W_lin, W_gate, Wp_gcn, Wp_lin, Wp_gate,
                                                   cnt, colsum, colsumsq, n);
    // 2. count in-edges per node
    k_count<<<(E + B - 1) / B, B, 0, stream>>>(eidx, cnt, E);
    // 3. exclusive scan -> offsets, init cursors
    k_scan1<<<nb, 256, 0, stream>>>(cnt, part, bsum, n);
    k_scan2<<<1, 256, 0, stream>>>(bsum, nb);
    k_scan3<<<nb, 256, 0, stream>>>(part, bsum, offs, cursor, n);
    // 4. scatter edges to CSR-by-dst
    k_scatter<<<(E + B - 1) / B, B, 0, stream>>>(eidx, cursor, csr_src, E);
    // 5. dinv + bf16 features (xscaled row-major, xs_p frag-linear)
    k_prep<<<(n * D_IN + B - 1) / B, B, 0, stream>>>(xs, cnt, dinv, xscaled, xs_p, n);
    // 6. gather aggregation (wave per node) -> agg_p frag-linear
    k_gather<<<(n + 3) / 4, B, 0, stream>>>(csr_src, offs, cnt, xscaled, dinv, agg_p, n);
    // 7. fused z-GEMM + gate-GEMM + lin-GEMM + epilogue + BN partials
    k_fused<<<npad / 64, B, 0, stream>>>(agg_p, xs_p, Wp_gcn, Wp_lin, Wp_gate,
                                         b_gcn, b_gate, b_lin, out_pre, colsum, colsumsq, n);
    // 8. BN finalize
    k_bn_final<<<1, D_HID, 0, stream>>>(colsum, colsumsq, gamma, beta, scale, shift, n);
    // 9. BN apply (bf16 -> fp32)
    {
        int total4 = n * D_HID / 4;
        k_bn_apply<<<(total4 + B - 1) / B, B, 0, stream>>>(out_pre, out, scale, shift, total4);
    }
}

// Round 7
// 295.036 us; speedup vs baseline: 3.4676x; 1.0129x over previous
//
#include <hip/hip_runtime.h>
#include <math.h>

#define NN 50000
#define NE 800000
#define D_IN 64
#define D_HID 256
#define BN_EPS 1e-5f
#define ZSTR 264   // z-tile LDS row stride in shorts (+8 pad: 16B-aligned rows, spread banks)

typedef __attribute__((ext_vector_type(8))) short short8;
typedef __attribute__((ext_vector_type(4))) float f32x4;

static __device__ __forceinline__ unsigned short f2bf(float f) {
    unsigned int u = __builtin_bit_cast(unsigned int, f);
    u += 0x7FFFu + ((u >> 16) & 1u);   // round-to-nearest-even
    return (unsigned short)(u >> 16);
}
static __device__ __forceinline__ float bf2f(unsigned short s) {
    unsigned int u = ((unsigned int)s) << 16;
    return __builtin_bit_cast(float, u);
}
// fast sigmoid: rcp(1+e^-x). Saturates cleanly at +/-inf, no NaN.
static __device__ __forceinline__ float fast_sigmoid(float x) {
    return __builtin_amdgcn_rcpf(1.0f + __expf(-x));
}
// fast tanh: 1 - 2*rcp(e^{2x}+1). Saturates cleanly, no NaN.
static __device__ __forceinline__ float fast_tanh(float x) {
    return 1.0f - 2.0f * __builtin_amdgcn_rcpf(__expf(2.0f * x) + 1.0f);
}

// ---------------- setup: zero counters/BN accums + pack all weights (one launch) ----------
// Wp[((ct*KC + kc)*64 + lane)*8 + j] = W[(kc*32 + (lane>>4)*8 + j)*256 + ct*16 + (lane&15)]
__global__ void k_setup(const float* __restrict__ W_gcn, const float* __restrict__ W_lin,
                        const float* __restrict__ W_gate,
                        unsigned short* __restrict__ Wp_gcn, unsigned short* __restrict__ Wp_lin,
                        unsigned short* __restrict__ Wp_gate,
                        int* __restrict__ cnt, float* __restrict__ colsum,
                        float* __restrict__ colsumsq, int n) {
    int idx = blockIdx.x * blockDim.x + threadIdx.x;
    if (idx < n) cnt[idx] = 0;
    if (idx < D_HID) { colsum[idx] = 0.f; colsumsq[idx] = 0.f; }
    if (idx >= 98304) return;
    const float* W;
    unsigned short* Wp;
    int KC, o;
    if (idx < 16384)      { W = W_gcn;  Wp = Wp_gcn;  KC = 2; o = idx; }
    else if (idx < 32768) { W = W_lin;  Wp = Wp_lin;  KC = 2; o = idx - 16384; }
    else                  { W = W_gate; Wp = Wp_gate; KC = 8; o = idx - 32768; }
    int j = o & 7;
    int lane = (o >> 3) & 63;
    int rest = o >> 9;
    int kc = rest % KC;
    int ct = rest / KC;
    int col = ct * 16 + (lane & 15);
    int k = kc * 32 + (lane >> 4) * 8 + j;
    Wp[o] = f2bf(W[k * D_HID + col]);
}

// ---------------- count in-edges per dst ----------------
__global__ void k_count(const int* __restrict__ eidx, int* __restrict__ cnt, int E) {
    int e = blockIdx.x * blockDim.x + threadIdx.x;
    if (e < E) atomicAdd(&cnt[eidx[E + e]], 1);
}

// ---------------- 2-level exclusive scan over cnt[n] ----------------
__global__ void k_scan1(const int* __restrict__ cnt, int* __restrict__ part,
                        int* __restrict__ bsum, int n) {
    __shared__ int s[256];
    int t = threadIdx.x;
    int i = blockIdx.x * 256 + t;
    int v = (i < n) ? cnt[i] : 0;
    s[t] = v;
    __syncthreads();
    for (int d = 1; d < 256; d <<= 1) {
        int t2 = (t >= d) ? s[t - d] : 0;
        __syncthreads();
        s[t] += t2;
        __syncthreads();
    }
    if (i < n) part[i] = s[t] - v;
    if (t == 255) bsum[blockIdx.x] = s[255];
}

__global__ void k_scan2(int* __restrict__ bsum, int nb) {
    __shared__ int s[256];
    int t = threadIdx.x;
    int v = (t < nb) ? bsum[t] : 0;
    s[t] = v;
    __syncthreads();
    for (int d = 1; d < 256; d <<= 1) {
        int t2 = (t >= d) ? s[t - d] : 0;
        __syncthreads();
        s[t] += t2;
        __syncthreads();
    }
    if (t < nb) bsum[t] = s[t] - v;
}

__global__ void k_scan3(const int* __restrict__ part, const int* __restrict__ bsum,
                        int* __restrict__ offs, int* __restrict__ cursor, int n) {
    int i = blockIdx.x * 256 + threadIdx.x;
    if (i < n) {
        int o = part[i] + bsum[blockIdx.x];
        offs[i] = o;
        cursor[i] = o;
    }
}

// ---------------- scatter edges into CSR-by-dst order ----------------
__global__ void k_scatter(const int* __restrict__ eidx, int* __restrict__ cursor,
                          int* __restrict__ csr_src, int E) {
    int e = blockIdx.x * blockDim.x + threadIdx.x;
    if (e >= E) return;
    int s = eidx[e];
    int d = eidx[E + e];
    int pos = atomicAdd(&cursor[d], 1);
    csr_src[pos] = s;
}

// A-frag-linear address for element (row i, feature k):
// ((i>>4)*2 + (k>>5))*512 + (((k>>3)&3)*16 + (i&15))*8 + (k&7)
static __device__ __forceinline__ long a_addr(int i, int k) {
    return ((long)((i >> 4) * 2 + (k >> 5)) << 9) + ((((k >> 3) & 3) * 16 + (i & 15)) << 3) + (k & 7);
}

// ---------------- dinv + bf16 features: xscaled row-major, xs_p frag-linear ----------------
__global__ void k_prep(const float* __restrict__ xs, const int* __restrict__ cnt,
                       float* __restrict__ dinv, unsigned short* __restrict__ xscaled,
                       unsigned short* __restrict__ xs_p, int n) {
    int idx = blockIdx.x * blockDim.x + threadIdx.x;  // over n*64
    if (idx >= n * D_IN) return;
    int i = idx >> 6;
    int k = idx & 63;
    float dv = rsqrtf(1.0f + (float)cnt[i]);
    float x = xs[idx];
    xscaled[idx] = f2bf(x * dv);
    xs_p[a_addr(i, k)] = f2bf(x);
    if (k == 0) dinv[i] = dv;
}

// ---------------- gather aggregation: wave per node, lane per feature ----------------
__global__ __launch_bounds__(256) void k_gather(const int* __restrict__ csr_src,
                                                const int* __restrict__ offs,
                                                const int* __restrict__ cnt,
                                                const unsigned short* __restrict__ xscaled,
                                                const float* __restrict__ dinv,
                                                unsigned short* __restrict__ agg_p, int n) {
    int wv = threadIdx.x >> 6;
    int lane = threadIdx.x & 63;
    int i = blockIdx.x * 4 + wv;
    if (i >= n) return;
    int start = offs[i];
    int c = cnt[i];
    float acc = bf2f(xscaled[(long)i * D_IN + lane]);  // self loop (pre-scaled)
    for (int base = 0; base < c; base += 64) {
        int m = c - base;
        m = m < 64 ? m : 64;
        int idx = (lane < m) ? csr_src[start + base + lane] : 0;
        int j = 0;
        for (; j + 8 <= m; j += 8) {
            int s0 = __shfl(idx, j + 0);
            int s1 = __shfl(idx, j + 1);
            int s2 = __shfl(idx, j + 2);
            int s3 = __shfl(idx, j + 3);
            int s4 = __shfl(idx, j + 4);
            int s5 = __shfl(idx, j + 5);
            int s6 = __shfl(idx, j + 6);
            int s7 = __shfl(idx, j + 7);
            float v0 = bf2f(xscaled[(long)s0 * D_IN + lane]);
            float v1 = bf2f(xscaled[(long)s1 * D_IN + lane]);
            float v2 = bf2f(xscaled[(long)s2 * D_IN + lane]);
            float v3 = bf2f(xscaled[(long)s3 * D_IN + lane]);
            float v4 = bf2f(xscaled[(long)s4 * D_IN + lane]);
            float v5 = bf2f(xscaled[(long)s5 * D_IN + lane]);
            float v6 = bf2f(xscaled[(long)s6 * D_IN + lane]);
            float v7 = bf2f(xscaled[(long)s7 * D_IN + lane]);
            acc += ((v0 + v1) + (v2 + v3)) + ((v4 + v5) + (v6 + v7));
        }
        for (; j < m; j++) {
            int s0 = __shfl(idx, j);
            acc += bf2f(xscaled[(long)s0 * D_IN + lane]);
        }
    }
    agg_p[a_addr(i, lane)] = f2bf(acc * dinv[i]);
}

// ---------------- fused: z GEMM -> LDS -> gate+lin GEMMs -> epilogue -> coalesced store ----
// block = 32 rows x 256 cols, 4 waves; wave wv owns cols [wv*64, wv*64+64)
// 32-row tile: halves accumulator VGPRs (no spills) and doubles grid (1564 blocks)
// vs round-6's 64-row tile whose launch_bounds forced 114MB of scratch spills.
__global__ void k_fused(const unsigned short* __restrict__ agg_p,
                        const unsigned short* __restrict__ xs_p,
                        const unsigned short* __restrict__ Wp_gcn,
                        const unsigned short* __restrict__ Wp_lin,
                        const unsigned short* __restrict__ Wp_gate,
                        const float* __restrict__ b_gcn,
                        const float* __restrict__ bg,
                        const float* __restrict__ bl,
                        unsigned short* __restrict__ out_pre,  // [npad][256]
                        float* __restrict__ colsum,
                        float* __restrict__ colsumsq, int n) {
    __shared__ unsigned short z_lds[32 * ZSTR];   // 16.9 KB

    int tid = threadIdx.x;
    int wv = tid >> 6;
    int lane = tid & 63;
    int l15 = lane & 15;
    int quad = lane >> 4;
    int row0 = blockIdx.x * 32;
    int rt0 = row0 >> 4;

    // ---- phase A: z = tanh(agg @ W_gcn + b_gcn), K=64, frag loads lane-coalesced ----
    {
        f32x4 accz[2][4];
#pragma unroll
        for (int a = 0; a < 2; a++)
#pragma unroll
            for (int c = 0; c < 4; c++) accz[a][c] = (f32x4){0.f, 0.f, 0.f, 0.f};
#pragma unroll
        for (int kc = 0; kc < 2; kc++) {
            short8 af[2];
#pragma unroll
            for (int tm = 0; tm < 2; tm++)
                af[tm] = *(const short8*)(agg_p + ((long)((rt0 + tm) * 2 + kc) << 9) + lane * 8);
            short8 bfr[4];
#pragma unroll
            for (int tn = 0; tn < 4; tn++)
                bfr[tn] = *(const short8*)(Wp_gcn + ((long)((wv * 4 + tn) * 2 + kc) << 9) + lane * 8);
#pragma unroll
            for (int tm = 0; tm < 2; tm++)
#pragma unroll
                for (int tn = 0; tn < 4; tn++)
                    accz[tm][tn] = __builtin_amdgcn_mfma_f32_16x16x32_bf16(af[tm], bfr[tn], accz[tm][tn], 0, 0, 0);
        }
#pragma unroll
        for (int tn = 0; tn < 4; tn++) {
            int col = wv * 64 + tn * 16 + l15;
            float bias = b_gcn[col];
#pragma unroll
            for (int tm = 0; tm < 2; tm++)
#pragma unroll
                for (int r2 = 0; r2 < 4; r2++) {
                    int rl = tm * 16 + quad * 4 + r2;
                    z_lds[rl * ZSTR + col] = f2bf(fast_tanh(accz[tm][tn][r2] + bias));
                }
        }
    }
    __syncthreads();

    // ---- phase B1: xl = xs @ W_lin, K=64 ----
    f32x4 acc2[2][4];
#pragma unroll
    for (int a = 0; a < 2; a++)
#pragma unroll
        for (int c = 0; c < 4; c++) acc2[a][c] = (f32x4){0.f, 0.f, 0.f, 0.f};
#pragma unroll
    for (int kc = 0; kc < 2; kc++) {
        short8 af[2];
#pragma unroll
        for (int tm = 0; tm < 2; tm++)
            af[tm] = *(const short8*)(xs_p + ((long)((rt0 + tm) * 2 + kc) << 9) + lane * 8);
        short8 bfr[4];
#pragma unroll
        for (int tn = 0; tn < 4; tn++)
            bfr[tn] = *(const short8*)(Wp_lin + ((long)((wv * 4 + tn) * 2 + kc) << 9) + lane * 8);
#pragma unroll
        for (int tm = 0; tm < 2; tm++)
#pragma unroll
            for (int tn = 0; tn < 4; tn++)
                acc2[tm][tn] = __builtin_amdgcn_mfma_f32_16x16x32_bf16(af[tm], bfr[tn], acc2[tm][tn], 0, 0, 0);
    }

    // ---- phase B2: logits = z @ W_gate, K=256, A from LDS, B lane-coalesced ----
    f32x4 acc1[2][4];
#pragma unroll
    for (int a = 0; a < 2; a++)
#pragma unroll
        for (int c = 0; c < 4; c++) acc1[a][c] = (f32x4){0.f, 0.f, 0.f, 0.f};
#pragma unroll
    for (int kc = 0; kc < 8; kc++) {
        short8 af[2];
#pragma unroll
        for (int tm = 0; tm < 2; tm++)
            af[tm] = *(const short8*)(&z_lds[(tm * 16 + l15) * ZSTR + kc * 32 + quad * 8]);
        short8 bfr[4];
#pragma unroll
        for (int tn = 0; tn < 4; tn++)
            bfr[tn] = *(const short8*)(Wp_gate + ((long)((wv * 4 + tn) * 8 + kc) << 9) + lane * 8);
#pragma unroll
        for (int tm = 0; tm < 2; tm++)
#pragma unroll
            for (int tn = 0; tn < 4; tn++)
                acc1[tm][tn] = __builtin_amdgcn_mfma_f32_16x16x32_bf16(af[tm], bfr[tn], acc1[tm][tn], 0, 0, 0);
    }
    __syncthreads();   // all B2 LDS reads done before in-place overwrite

    // ---- epilogue: o = relu((1-g)*xl + g*z); write o back into z_lds; BN partials ----
    float ls[4] = {0.f, 0.f, 0.f, 0.f};
    float lsq[4] = {0.f, 0.f, 0.f, 0.f};
#pragma unroll
    for (int tn = 0; tn < 4; tn++) {
        int col = wv * 64 + tn * 16 + l15;
        float bgc = bg[col];
        float blc = bl[col];
#pragma unroll
        for (int tm = 0; tm < 2; tm++)
#pragma unroll
            for (int r2 = 0; r2 < 4; r2++) {
                int rl = tm * 16 + quad * 4 + r2;
                int row = row0 + rl;
                if (row < n) {
                    float g = fast_sigmoid(acc1[tm][tn][r2] + bgc);
                    float zv = bf2f(z_lds[rl * ZSTR + col]);
                    float xv = acc2[tm][tn][r2] + blc;
                    float o = fmaxf((1.f - g) * xv + g * zv, 0.f);
                    z_lds[rl * ZSTR + col] = f2bf(o);
                    ls[tn] += o;
                    lsq[tn] += o * o;
                }
            }
    }
    __syncthreads();

    // ---- coalesced tile store: 4 x dwordx4 per thread ----
#pragma unroll
    for (int it = 0; it < 4; it++) {
        int g = it * 2048 + tid * 8;       // shorts within 32x256 tile
        int row = g >> 8;
        int col = g & 255;
        short8 v = *(const short8*)(&z_lds[row * ZSTR + col]);
        *(short8*)(out_pre + (long)(row0 + row) * D_HID + col) = v;
    }

    // ---- BN partial atomics last (lets the tile store drain first) ----
#pragma unroll
    for (int tn = 0; tn < 4; tn++) {
        float s = ls[tn];
        float q = lsq[tn];
        s += __shfl_xor(s, 16);
        s += __shfl_xor(s, 32);
        q += __shfl_xor(q, 16);
        q += __shfl_xor(q, 32);
        if (quad == 0) {
            int col = wv * 64 + tn * 16 + l15;
            atomicAdd(&colsum[col], s);
            atomicAdd(&colsumsq[col], q);
        }
    }
}

// ---------------- BN finalize: per-column scale/shift ----------------
__global__ void k_bn_final(const float* __restrict__ colsum, const float* __restrict__ colsumsq,
                           const float* __restrict__ gamma, const float* __restrict__ beta,
                           float* __restrict__ scale, float* __restrict__ shift, int n) {
    int c = threadIdx.x;
    float inv_n = 1.0f / (float)n;
    float mu = colsum[c] * inv_n;
    float var = colsumsq[c] * inv_n - mu * mu;
    float sc = gamma[c] * rsqrtf(var + BN_EPS);
    scale[c] = sc;
    shift[c] = beta[c] - mu * sc;
}

// ---------------- BN apply: bf16 in -> fp32 out ----------------
__global__ void k_bn_apply(const unsigned short* __restrict__ op, float* __restrict__ out,
                           const float* __restrict__ scale, const float* __restrict__ shift,
                           int total4) {
    int i4 = blockIdx.x * blockDim.x + threadIdx.x;
    if (i4 >= total4) return;
    long idx = (long)i4 * 4;
    ushort2 p0 = *(const ushort2*)(op + idx);
    ushort2 p1 = *(const ushort2*)(op + idx + 2);
    int c = (int)(idx & (D_HID - 1));
    float4 v;
    v.x = bf2f(p0.x) * scale[c + 0] + shift[c + 0];
    v.y = bf2f(p0.y) * scale[c + 1] + shift[c + 1];
    v.z = bf2f(p1.x) * scale[c + 2] + shift[c + 2];
    v.w = bf2f(p1.y) * scale[c + 3] + shift[c + 3];
    *(float4*)(out + idx) = v;
}

extern "C" void kernel_launch(void* const* d_in, const int* in_sizes, int n_in,
                              void* d_out, int out_size, void* d_ws, size_t ws_size,
                              hipStream_t stream) {
    const float* xs     = (const float*)d_in[0];
    const int*   eidx   = (const int*)d_in[1];
    const float* W_gcn  = (const float*)d_in[2];
    const float* b_gcn  = (const float*)d_in[3];
    const float* W_lin  = (const float*)d_in[4];
    const float* b_lin  = (const float*)d_in[5];
    const float* W_gate = (const float*)d_in[6];
    const float* b_gate = (const float*)d_in[7];
    const float* gamma  = (const float*)d_in[8];
    const float* beta   = (const float*)d_in[9];
    float* out = (float*)d_out;

    const int n = in_sizes[0] / D_IN;   // 50000
    const int E = in_sizes[1] / 2;      // 800000
    const int npad = (n + 63) & ~63;

    // workspace layout (512B aligned)
    char* ws = (char*)d_ws;
    size_t off = 0;
    auto alloc = [&](size_t bytes) {
        char* p = ws + off;
        off += (bytes + 511) & ~(size_t)511;
        return p;
    };
    int*            cnt      = (int*)alloc((size_t)n * 4);
    int*            part     = (int*)alloc((size_t)n * 4);
    int*            bsum     = (int*)alloc(1024);
    int*            offs     = (int*)alloc((size_t)n * 4);
    int*            cursor   = (int*)alloc((size_t)n * 4);
    int*            csr_src  = (int*)alloc((size_t)E * 4);
    float*          dinv     = (float*)alloc((size_t)n * 4);
    unsigned short* xscaled  = (unsigned short*)alloc((size_t)n * D_IN * 2);
    unsigned short* xs_p     = (unsigned short*)alloc((size_t)npad * D_IN * 2);
    unsigned short* agg_p    = (unsigned short*)alloc((size_t)npad * D_IN * 2);
    unsigned short* out_pre  = (unsigned short*)alloc((size_t)npad * D_HID * 2);
    unsigned short* Wp_gcn   = (unsigned short*)alloc((size_t)D_IN * D_HID * 2);
    unsigned short* Wp_lin   = (unsigned short*)alloc((size_t)D_IN * D_HID * 2);
    unsigned short* Wp_gate  = (unsigned short*)alloc((size_t)D_HID * D_HID * 2);
    float*          colsum   = (float*)alloc(D_HID * 4);
    float*          colsumsq = (float*)alloc(D_HID * 4);
    float*          scale    = (float*)alloc(D_HID * 4);
    float*          shift    = (float*)alloc(D_HID * 4);
    (void)ws_size;

    const int B = 256;
    const int nb = (n + 255) / 256;

    // 1. setup: zero counters/BN accums + pack weights (single launch)
    k_setup<<<(98304 + B - 1) / B, B, 0, stream>>>(W_gcn, W_lin, W_gate, Wp_gcn, Wp_lin, Wp_gate,
                                                   cnt, colsum, colsumsq, n);
    // 2. count in-edges per node
    k_count<<<(E + B - 1) / B, B, 0, stream>>>(eidx, cnt, E);
    // 3. exclusive scan -> offsets, init cursors
    k_scan1<<<nb, 256, 0, stream>>>(cnt, part, bsum, n);
    k_scan2<<<1, 256, 0, stream>>>(bsum, nb);
    k_scan3<<<nb, 256, 0, stream>>>(part, bsum, offs, cursor, n);
    // 4. scatter edges to CSR-by-dst
    k_scatter<<<(E + B - 1) / B, B, 0, stream>>>(eidx, cursor, csr_src, E);
    // 5. dinv + bf16 features (xscaled row-major, xs_p frag-linear)
    k_prep<<<(n * D_IN + B - 1) / B, B, 0, stream>>>(xs, cnt, dinv, xscaled, xs_p, n);
    // 6. gather aggregation (wave per node) -> agg_p frag-linear
    k_gather<<<(n + 3) / 4, B, 0, stream>>>(csr_src, offs, cnt, xscaled, dinv, agg_p, n);
    // 7. fused z-GEMM + gate-GEMM + lin-GEMM + epilogue + BN partials (32-row tiles)
    k_fused<<<npad / 32, B, 0, stream>>>(agg_p, xs_p, Wp_gcn, Wp_lin, Wp_gate,
                                         b_gcn, b_gate, b_lin, out_pre, colsum, colsumsq, n);
    // 8. BN finalize
    k_bn_final<<<1, D_HID, 0, stream>>>(colsum, colsumsq, gamma, beta, scale, shift, n);
    // 9. BN apply (bf16 -> fp32)
    {
        int total4 = n * D_HID / 4;
        k_bn_apply<<<(total4 + B - 1) / B, B, 0, stream>>>(out_pre, out, scale, shift, total4);
    }
}

// Round 8
// 285.379 us; speedup vs baseline: 3.5849x; 1.0338x over previous
//
#include <hip/hip_runtime.h>
#include <math.h>

#define NN 50000
#define NE 800000
#define D_IN 64
#define D_HID 256
#define BN_EPS 1e-5f
#define ZSTR 264   // LDS tile row stride in shorts (+8 pad: 16B-aligned rows, spread banks)

typedef __attribute__((ext_vector_type(8))) short short8;
typedef __attribute__((ext_vector_type(4))) float f32x4;

static __device__ __forceinline__ unsigned short f2bf(float f) {
    unsigned int u = __builtin_bit_cast(unsigned int, f);
    u += 0x7FFFu + ((u >> 16) & 1u);   // round-to-nearest-even
    return (unsigned short)(u >> 16);
}
static __device__ __forceinline__ float bf2f(unsigned short s) {
    unsigned int u = ((unsigned int)s) << 16;
    return __builtin_bit_cast(float, u);
}
// fast sigmoid: rcp(1+e^-x). Saturates cleanly at +/-inf, no NaN.
static __device__ __forceinline__ float fast_sigmoid(float x) {
    return __builtin_amdgcn_rcpf(1.0f + __expf(-x));
}
// fast tanh: 1 - 2*rcp(e^{2x}+1). Saturates cleanly, no NaN.
static __device__ __forceinline__ float fast_tanh(float x) {
    return 1.0f - 2.0f * __builtin_amdgcn_rcpf(__expf(2.0f * x) + 1.0f);
}

// ---------------- setup: zero counters/BN accums + pack all weights (one launch) ----------
// Wp[((ct*KC + kc)*64 + lane)*8 + j] = W[(kc*32 + (lane>>4)*8 + j)*256 + ct*16 + (lane&15)]
__global__ void k_setup(const float* __restrict__ W_gcn, const float* __restrict__ W_lin,
                        const float* __restrict__ W_gate,
                        unsigned short* __restrict__ Wp_gcn, unsigned short* __restrict__ Wp_lin,
                        unsigned short* __restrict__ Wp_gate,
                        int* __restrict__ cnt, float* __restrict__ colsum,
                        float* __restrict__ colsumsq, int n) {
    int idx = blockIdx.x * blockDim.x + threadIdx.x;
    if (idx < n) cnt[idx] = 0;
    if (idx < D_HID) { colsum[idx] = 0.f; colsumsq[idx] = 0.f; }
    if (idx >= 98304) return;
    const float* W;
    unsigned short* Wp;
    int KC, o;
    if (idx < 16384)      { W = W_gcn;  Wp = Wp_gcn;  KC = 2; o = idx; }
    else if (idx < 32768) { W = W_lin;  Wp = Wp_lin;  KC = 2; o = idx - 16384; }
    else                  { W = W_gate; Wp = Wp_gate; KC = 8; o = idx - 32768; }
    int j = o & 7;
    int lane = (o >> 3) & 63;
    int rest = o >> 9;
    int kc = rest % KC;
    int ct = rest / KC;
    int col = ct * 16 + (lane & 15);
    int k = kc * 32 + (lane >> 4) * 8 + j;
    Wp[o] = f2bf(W[k * D_HID + col]);
}

// ---------------- count in-edges per dst ----------------
__global__ void k_count(const int* __restrict__ eidx, int* __restrict__ cnt, int E) {
    int e = blockIdx.x * blockDim.x + threadIdx.x;
    if (e < E) atomicAdd(&cnt[eidx[E + e]], 1);
}

// ---------------- 2-level exclusive scan over cnt[n] ----------------
__global__ void k_scan1(const int* __restrict__ cnt, int* __restrict__ part,
                        int* __restrict__ bsum, int n) {
    __shared__ int s[256];
    int t = threadIdx.x;
    int i = blockIdx.x * 256 + t;
    int v = (i < n) ? cnt[i] : 0;
    s[t] = v;
    __syncthreads();
    for (int d = 1; d < 256; d <<= 1) {
        int t2 = (t >= d) ? s[t - d] : 0;
        __syncthreads();
        s[t] += t2;
        __syncthreads();
    }
    if (i < n) part[i] = s[t] - v;
    if (t == 255) bsum[blockIdx.x] = s[255];
}

__global__ void k_scan2(int* __restrict__ bsum, int nb) {
    __shared__ int s[256];
    int t = threadIdx.x;
    int v = (t < nb) ? bsum[t] : 0;
    s[t] = v;
    __syncthreads();
    for (int d = 1; d < 256; d <<= 1) {
        int t2 = (t >= d) ? s[t - d] : 0;
        __syncthreads();
        s[t] += t2;
        __syncthreads();
    }
    if (t < nb) bsum[t] = s[t] - v;
}

// A-frag-linear address for element (row i, feature k):
// ((i>>4)*2 + (k>>5))*512 + (((k>>3)&3)*16 + (i&15))*8 + (k&7)
static __device__ __forceinline__ long a_addr(int i, int k) {
    return ((long)((i >> 4) * 2 + (k >> 5)) << 9) + ((((k >> 3) & 3) * 16 + (i & 15)) << 3) + (k & 7);
}

// ---------------- scan fixup + prep fused: offs/cursor + dinv + bf16 features ------------
// grid covers n*8 threads; thread (i, sub) handles features sub*8..sub*8+7 of node i.
__global__ void k_scan3p(const int* __restrict__ part, const int* __restrict__ bsum,
                         int* __restrict__ offs, int* __restrict__ cursor,
                         const float* __restrict__ xs, const int* __restrict__ cnt,
                         float* __restrict__ dinv, unsigned short* __restrict__ xscaled,
                         unsigned short* __restrict__ xs_p, int n) {
    int idx = blockIdx.x * 256 + threadIdx.x;
    if (idx < n) {
        int o = part[idx] + bsum[idx >> 8];
        offs[idx] = o;
        cursor[idx] = o;
    }
    if (idx >= n * 8) return;
    int i = idx >> 3;
    int sub = idx & 7;
    float dv = rsqrtf(1.0f + (float)cnt[i]);
    if (sub == 0) dinv[i] = dv;
    const float* p = xs + (long)i * D_IN + sub * 8;
    float4 f0 = *(const float4*)p;
    float4 f1 = *(const float4*)(p + 4);
    float vals[8] = {f0.x, f0.y, f0.z, f0.w, f1.x, f1.y, f1.z, f1.w};
    short8 xsc, xsb;
#pragma unroll
    for (int j = 0; j < 8; j++) {
        xsc[j] = (short)f2bf(vals[j] * dv);
        xsb[j] = (short)f2bf(vals[j]);
    }
    *(short8*)(xscaled + (long)i * D_IN + sub * 8) = xsc;
    *(short8*)(xs_p + a_addr(i, sub * 8)) = xsb;
}

// ---------------- scatter edges into CSR-by-dst order ----------------
__global__ void k_scatter(const int* __restrict__ eidx, int* __restrict__ cursor,
                          int* __restrict__ csr_src, int E) {
    int e = blockIdx.x * blockDim.x + threadIdx.x;
    if (e >= E) return;
    int s = eidx[e];
    int d = eidx[E + e];
    int pos = atomicAdd(&cursor[d], 1);
    csr_src[pos] = s;
}

// ---------------- gather aggregation: wave per node, 8 rows x 16B/lane per round ---------
// lane = (grp = lane>>3: row slot, sub = lane&7: feature octet). Each wave round gathers
// 8 neighbor rows with dwordx4 loads (1KB/wave/instr) vs round-7's 1 row at 2B/lane.
__global__ __launch_bounds__(256) void k_gather(const int* __restrict__ csr_src,
                                                const int* __restrict__ offs,
                                                const int* __restrict__ cnt,
                                                const unsigned short* __restrict__ xscaled,
                                                const float* __restrict__ dinv,
                                                unsigned short* __restrict__ agg_p, int n) {
    int wv = threadIdx.x >> 6;
    int lane = threadIdx.x & 63;
    int sub = lane & 7;
    int grp = lane >> 3;
    int i = blockIdx.x * 4 + wv;
    if (i >= n) return;
    int start = offs[i];
    int c = cnt[i];
    float acc[8];
#pragma unroll
    for (int j = 0; j < 8; j++) acc[j] = 0.f;
    for (int base = 0; base < c; base += 64) {
        int m = c - base;
        m = m < 64 ? m : 64;
        int idxv = (lane < m) ? csr_src[start + base + lane] : 0;
#pragma unroll
        for (int t = 0; t < 8; t++) {
            int e = t * 8 + grp;
            int row = __shfl(idxv, e);
            if (e < m) {
                short8 v = *(const short8*)(xscaled + (long)row * D_IN + sub * 8);
#pragma unroll
                for (int j = 0; j < 8; j++) acc[j] += bf2f((unsigned short)v[j]);
            }
        }
    }
    // reduce across the 8 row slots (lane bits 3..5)
#pragma unroll
    for (int d = 8; d <= 32; d <<= 1)
#pragma unroll
        for (int j = 0; j < 8; j++) acc[j] += __shfl_xor(acc[j], d);
    if (grp == 0) {
        float dv = dinv[i];
        short8 sv = *(const short8*)(xscaled + (long)i * D_IN + sub * 8);  // self loop
        short8 o;
#pragma unroll
        for (int j = 0; j < 8; j++)
            o[j] = (short)f2bf((acc[j] + bf2f((unsigned short)sv[j])) * dv);
        *(short8*)(agg_p + a_addr(i, sub * 8)) = o;
    }
}

// ---------------- fused: z GEMM -> LDS; lin GEMM pre-barrier; gate GEMM; epilogue --------
// block = 32 rows x 256 cols, 4 waves; wave wv owns cols [wv*64, wv*64+64). 2 barriers.
__global__ void k_fused(const unsigned short* __restrict__ agg_p,
                        const unsigned short* __restrict__ xs_p,
                        const unsigned short* __restrict__ Wp_gcn,
                        const unsigned short* __restrict__ Wp_lin,
                        const unsigned short* __restrict__ Wp_gate,
                        const float* __restrict__ b_gcn,
                        const float* __restrict__ bg,
                        const float* __restrict__ bl,
                        unsigned short* __restrict__ out_pre,  // [npad][256]
                        float* __restrict__ colsum,
                        float* __restrict__ colsumsq, int n) {
    __shared__ unsigned short z_lds[32 * ZSTR];   // 16.9 KB
    __shared__ unsigned short o_lds[32 * ZSTR];   // 16.9 KB (separate: kills a barrier)

    int tid = threadIdx.x;
    int wv = tid >> 6;
    int lane = tid & 63;
    int l15 = lane & 15;
    int quad = lane >> 4;
    int row0 = blockIdx.x * 32;
    int rt0 = row0 >> 4;

    // ---- phase A: z = tanh(agg @ W_gcn + b_gcn), K=64 ----
    {
        f32x4 accz[2][4];
#pragma unroll
        for (int a = 0; a < 2; a++)
#pragma unroll
            for (int c = 0; c < 4; c++) accz[a][c] = (f32x4){0.f, 0.f, 0.f, 0.f};
#pragma unroll
        for (int kc = 0; kc < 2; kc++) {
            short8 af[2];
#pragma unroll
            for (int tm = 0; tm < 2; tm++)
                af[tm] = *(const short8*)(agg_p + ((long)((rt0 + tm) * 2 + kc) << 9) + lane * 8);
            short8 bfr[4];
#pragma unroll
            for (int tn = 0; tn < 4; tn++)
                bfr[tn] = *(const short8*)(Wp_gcn + ((long)((wv * 4 + tn) * 2 + kc) << 9) + lane * 8);
#pragma unroll
            for (int tm = 0; tm < 2; tm++)
#pragma unroll
                for (int tn = 0; tn < 4; tn++)
                    accz[tm][tn] = __builtin_amdgcn_mfma_f32_16x16x32_bf16(af[tm], bfr[tn], accz[tm][tn], 0, 0, 0);
        }
#pragma unroll
        for (int tn = 0; tn < 4; tn++) {
            int col = wv * 64 + tn * 16 + l15;
            float bias = b_gcn[col];
#pragma unroll
            for (int tm = 0; tm < 2; tm++)
#pragma unroll
                for (int r2 = 0; r2 < 4; r2++) {
                    int rl = tm * 16 + quad * 4 + r2;
                    z_lds[rl * ZSTR + col] = f2bf(fast_tanh(accz[tm][tn][r2] + bias));
                }
        }
    }

    // ---- phase B1 (independent of z_lds — runs while LDS writes drain): xl = xs @ W_lin ----
    f32x4 acc2[2][4];
#pragma unroll
    for (int a = 0; a < 2; a++)
#pragma unroll
        for (int c = 0; c < 4; c++) acc2[a][c] = (f32x4){0.f, 0.f, 0.f, 0.f};
#pragma unroll
    for (int kc = 0; kc < 2; kc++) {
        short8 af[2];
#pragma unroll
        for (int tm = 0; tm < 2; tm++)
            af[tm] = *(const short8*)(xs_p + ((long)((rt0 + tm) * 2 + kc) << 9) + lane * 8);
        short8 bfr[4];
#pragma unroll
        for (int tn = 0; tn < 4; tn++)
            bfr[tn] = *(const short8*)(Wp_lin + ((long)((wv * 4 + tn) * 2 + kc) << 9) + lane * 8);
#pragma unroll
        for (int tm = 0; tm < 2; tm++)
#pragma unroll
            for (int tn = 0; tn < 4; tn++)
                acc2[tm][tn] = __builtin_amdgcn_mfma_f32_16x16x32_bf16(af[tm], bfr[tn], acc2[tm][tn], 0, 0, 0);
    }
    __syncthreads();

    // ---- phase B2: logits = z @ W_gate, K=256, A from LDS, B lane-coalesced ----
    f32x4 acc1[2][4];
#pragma unroll
    for (int a = 0; a < 2; a++)
#pragma unroll
        for (int c = 0; c < 4; c++) acc1[a][c] = (f32x4){0.f, 0.f, 0.f, 0.f};
#pragma unroll
    for (int kc = 0; kc < 8; kc++) {
        short8 af[2];
#pragma unroll
        for (int tm = 0; tm < 2; tm++)
            af[tm] = *(const short8*)(&z_lds[(tm * 16 + l15) * ZSTR + kc * 32 + quad * 8]);
        short8 bfr[4];
#pragma unroll
        for (int tn = 0; tn < 4; tn++)
            bfr[tn] = *(const short8*)(Wp_gate + ((long)((wv * 4 + tn) * 8 + kc) << 9) + lane * 8);
#pragma unroll
        for (int tm = 0; tm < 2; tm++)
#pragma unroll
            for (int tn = 0; tn < 4; tn++)
                acc1[tm][tn] = __builtin_amdgcn_mfma_f32_16x16x32_bf16(af[tm], bfr[tn], acc1[tm][tn], 0, 0, 0);
    }

    // ---- epilogue: o = relu((1-g)*xl + g*z) -> o_lds; BN partials ----
    float ls[4] = {0.f, 0.f, 0.f, 0.f};
    float lsq[4] = {0.f, 0.f, 0.f, 0.f};
#pragma unroll
    for (int tn = 0; tn < 4; tn++) {
        int col = wv * 64 + tn * 16 + l15;
        float bgc = bg[col];
        float blc = bl[col];
#pragma unroll
        for (int tm = 0; tm < 2; tm++)
#pragma unroll
            for (int r2 = 0; r2 < 4; r2++) {
                int rl = tm * 16 + quad * 4 + r2;
                int row = row0 + rl;
                if (row < n) {
                    float g = fast_sigmoid(acc1[tm][tn][r2] + bgc);
                    float zv = bf2f(z_lds[rl * ZSTR + col]);
                    float xv = acc2[tm][tn][r2] + blc;
                    float o = fmaxf((1.f - g) * xv + g * zv, 0.f);
                    o_lds[rl * ZSTR + col] = f2bf(o);
                    ls[tn] += o;
                    lsq[tn] += o * o;
                }
            }
    }
    __syncthreads();

    // ---- coalesced tile store: 4 x dwordx4 per thread ----
#pragma unroll
    for (int it = 0; it < 4; it++) {
        int g = it * 2048 + tid * 8;       // shorts within 32x256 tile
        int row = g >> 8;
        int col = g & 255;
        short8 v = *(const short8*)(&o_lds[row * ZSTR + col]);
        *(short8*)(out_pre + (long)(row0 + row) * D_HID + col) = v;
    }

    // ---- BN partial atomics last (lets the tile store drain first) ----
#pragma unroll
    for (int tn = 0; tn < 4; tn++) {
        float s = ls[tn];
        float q = lsq[tn];
        s += __shfl_xor(s, 16);
        s += __shfl_xor(s, 32);
        q += __shfl_xor(q, 16);
        q += __shfl_xor(q, 32);
        if (quad == 0) {
            int col = wv * 64 + tn * 16 + l15;
            atomicAdd(&colsum[col], s);
            atomicAdd(&colsumsq[col], q);
        }
    }
}

// ---------------- BN finalize: per-column scale/shift ----------------
__global__ void k_bn_final(const float* __restrict__ colsum, const float* __restrict__ colsumsq,
                           const float* __restrict__ gamma, const float* __restrict__ beta,
                           float* __restrict__ scale, float* __restrict__ shift, int n) {
    int c = threadIdx.x;
    float inv_n = 1.0f / (float)n;
    float mu = colsum[c] * inv_n;
    float var = colsumsq[c] * inv_n - mu * mu;
    float sc = gamma[c] * rsqrtf(var + BN_EPS);
    scale[c] = sc;
    shift[c] = beta[c] - mu * sc;
}

// ---------------- BN apply: bf16 in -> fp32 out, 8 elems/thread ----------------
__global__ void k_bn_apply(const unsigned short* __restrict__ op, float* __restrict__ out,
                           const float* __restrict__ scale, const float* __restrict__ shift,
                           int total8) {
    int i8 = blockIdx.x * blockDim.x + threadIdx.x;
    if (i8 >= total8) return;
    long idx = (long)i8 * 8;
    short8 p = *(const short8*)(op + idx);
    int c = (int)(idx & (D_HID - 1));
    float4 s0 = *(const float4*)(scale + c);
    float4 s1 = *(const float4*)(scale + c + 4);
    float4 h0 = *(const float4*)(shift + c);
    float4 h1 = *(const float4*)(shift + c + 4);
    float4 v0, v1;
    v0.x = bf2f((unsigned short)p[0]) * s0.x + h0.x;
    v0.y = bf2f((unsigned short)p[1]) * s0.y + h0.y;
    v0.z = bf2f((unsigned short)p[2]) * s0.z + h0.z;
    v0.w = bf2f((unsigned short)p[3]) * s0.w + h0.w;
    v1.x = bf2f((unsigned short)p[4]) * s1.x + h1.x;
    v1.y = bf2f((unsigned short)p[5]) * s1.y + h1.y;
    v1.z = bf2f((unsigned short)p[6]) * s1.z + h1.z;
    v1.w = bf2f((unsigned short)p[7]) * s1.w + h1.w;
    *(float4*)(out + idx) = v0;
    *(float4*)(out + idx + 4) = v1;
}

extern "C" void kernel_launch(void* const* d_in, const int* in_sizes, int n_in,
                              void* d_out, int out_size, void* d_ws, size_t ws_size,
                              hipStream_t stream) {
    const float* xs     = (const float*)d_in[0];
    const int*   eidx   = (const int*)d_in[1];
    const float* W_gcn  = (const float*)d_in[2];
    const float* b_gcn  = (const float*)d_in[3];
    const float* W_lin  = (const float*)d_in[4];
    const float* b_lin  = (const float*)d_in[5];
    const float* W_gate = (const float*)d_in[6];
    const float* b_gate = (const float*)d_in[7];
    const float* gamma  = (const float*)d_in[8];
    const float* beta   = (const float*)d_in[9];
    float* out = (float*)d_out;

    const int n = in_sizes[0] / D_IN;   // 50000
    const int E = in_sizes[1] / 2;      // 800000
    const int npad = (n + 63) & ~63;

    // workspace layout (512B aligned)
    char* ws = (char*)d_ws;
    size_t off = 0;
    auto alloc = [&](size_t bytes) {
        char* p = ws + off;
        off += (bytes + 511) & ~(size_t)511;
        return p;
    };
    int*            cnt      = (int*)alloc((size_t)n * 4);
    int*            part     = (int*)alloc((size_t)n * 4);
    int*            bsum     = (int*)alloc(1024);
    int*            offs     = (int*)alloc((size_t)n * 4);
    int*            cursor   = (int*)alloc((size_t)n * 4);
    int*            csr_src  = (int*)alloc((size_t)E * 4);
    float*          dinv     = (float*)alloc((size_t)n * 4);
    unsigned short* xscaled  = (unsigned short*)alloc((size_t)n * D_IN * 2);
    unsigned short* xs_p     = (unsigned short*)alloc((size_t)npad * D_IN * 2);
    unsigned short* agg_p    = (unsigned short*)alloc((size_t)npad * D_IN * 2);
    unsigned short* out_pre  = (unsigned short*)alloc((size_t)npad * D_HID * 2);
    unsigned short* Wp_gcn   = (unsigned short*)alloc((size_t)D_IN * D_HID * 2);
    unsigned short* Wp_lin   = (unsigned short*)alloc((size_t)D_IN * D_HID * 2);
    unsigned short* Wp_gate  = (unsigned short*)alloc((size_t)D_HID * D_HID * 2);
    float*          colsum   = (float*)alloc(D_HID * 4);
    float*          colsumsq = (float*)alloc(D_HID * 4);
    float*          scale    = (float*)alloc(D_HID * 4);
    float*          shift    = (float*)alloc(D_HID * 4);
    (void)ws_size;

    const int B = 256;
    const int nb = (n + 255) / 256;

    // 1. setup: zero counters/BN accums + pack weights
    k_setup<<<(98304 + B - 1) / B, B, 0, stream>>>(W_gcn, W_lin, W_gate, Wp_gcn, Wp_lin, Wp_gate,
                                                   cnt, colsum, colsumsq, n);
    // 2. count in-edges per node
    k_count<<<(E + B - 1) / B, B, 0, stream>>>(eidx, cnt, E);
    // 3. exclusive scan; fixup fused with feature prep
    k_scan1<<<nb, 256, 0, stream>>>(cnt, part, bsum, n);
    k_scan2<<<1, 256, 0, stream>>>(bsum, nb);
    k_scan3p<<<(n * 8 + B - 1) / B, B, 0, stream>>>(part, bsum, offs, cursor,
                                                    xs, cnt, dinv, xscaled, xs_p, n);
    // 4. scatter edges to CSR-by-dst
    k_scatter<<<(E + B - 1) / B, B, 0, stream>>>(eidx, cursor, csr_src, E);
    // 5. gather aggregation (wave per node, 8 rows/round, 16B/lane)
    k_gather<<<(n + 3) / 4, B, 0, stream>>>(csr_src, offs, cnt, xscaled, dinv, agg_p, n);
    // 6. fused z-GEMM + gate-GEMM + lin-GEMM + epilogue + BN partials (32-row tiles)
    k_fused<<<npad / 32, B, 0, stream>>>(agg_p, xs_p, Wp_gcn, Wp_lin, Wp_gate,
                                         b_gcn, b_gate, b_lin, out_pre, colsum, colsumsq, n);
    // 7. BN finalize
    k_bn_final<<<1, D_HID, 0, stream>>>(colsum, colsumsq, gamma, beta, scale, shift, n);
    // 8. BN apply (bf16 -> fp32)
    {
        int total8 = n * D_HID / 8;
        k_bn_apply<<<(total8 + B - 1) / B, B, 0, stream>>>(out_pre, out, scale, shift, total8);
    }
}